// Round 1
// 1373.054 us; speedup vs baseline: 1.1358x; 1.1358x over previous
//
#include <hip/hip_runtime.h>
#include <math.h>

#define N_NODES 50000
#define E_EDGES 800000
#define EP_EDGES 200000
#define NG4 (4 * N_NODES)
#define ETOT (4 * E_EDGES)

static inline int idiv(int a, int b) { return (a + b - 1) / b; }

typedef short s16x8 __attribute__((ext_vector_type(8)));
typedef float f32x4 __attribute__((ext_vector_type(4)));
typedef unsigned short us;

static __device__ __forceinline__ us f2bf(float f) {
  unsigned int u = __float_as_uint(f);
  u += 0x7FFFu + ((u >> 16) & 1u);
  return (us)(u >> 16);
}
static __device__ __forceinline__ float bflo(unsigned int u) { return __uint_as_float(u << 16); }
static __device__ __forceinline__ float bfhi(unsigned int u) { return __uint_as_float(u & 0xffff0000u); }

// ---------------- fused weight transpose+convert: 7 segments via blockIdx.z ----------------
__global__ __launch_bounds__(256) void wtrans_all_k(
    const float* __restrict__ W2, const float* __restrict__ W1,
    const float* __restrict__ gWs, const float* __restrict__ gWd,
    const float* __restrict__ prW1, const float* __restrict__ pW1,
    const float* __restrict__ gaW1,
    us* __restrict__ W2t, us* __restrict__ W1t, us* __restrict__ gWst,
    us* __restrict__ gWdt, us* __restrict__ prW1t, us* __restrict__ WaPt,
    us* __restrict__ WaGt)
{
  const float* src; us* dst; int ks, nsh, total;
  switch (blockIdx.z) {
    case 0: src = W2;   dst = W2t;   ks = 10; nsh = 8; total = 262144; break;
    case 1: src = W1;   dst = W1t;   ks = 9;  nsh = 8; total = 131072; break;
    case 2: src = gWs;  dst = gWst;  ks = 8;  nsh = 7; total = 131072; break;
    case 3: src = gWd;  dst = gWdt;  ks = 8;  nsh = 7; total = 131072; break;
    case 4: src = prW1; dst = prW1t; ks = 8;  nsh = 7; total = 32768;  break;
    case 5: src = pW1;  dst = WaPt;  ks = 7;  nsh = 7; total = 16384;  break;
    default: src = gaW1; dst = WaGt; ks = 7;  nsh = 7; total = 16384;  break;
  }
  int psh = ks + nsh;
  int Km1 = (1 << ks) - 1;
  int pm1 = (1 << psh) - 1;
  for (int gid = blockIdx.x * 256 + threadIdx.x; gid < total; gid += gridDim.x * 256) {
    int mat = gid >> psh;
    int rem = gid & pm1;
    int n = rem >> ks, k = rem & Km1;
    dst[gid] = f2bf(src[((size_t)mat << psh) + ((size_t)k << nsh) + n]);
  }
}

// ------- projection GEMM with fused f32->bf16 A conversion: C[M,256] = bf16(A[M,K]) @ Bt^T + bias -------
// Tile 128 rows x 256 cols (full width); 4 waves as 2x2, each wave 64x128 (4x8 mfma frags).
__global__ __launch_bounds__(256) void proj_gemm_k(
    const float* __restrict__ A, const us* __restrict__ Bt,
    const float* __restrict__ bias, us* __restrict__ C, int M, int K)
{
  __shared__ us As[128 * 40];
  __shared__ us Bs[256 * 40];
  const int t = threadIdx.x;
  const int rowBase = blockIdx.x * 128;
  const int srow = t >> 1, sk = (t & 1) * 16;
  const int w = t >> 6, lane = t & 63;
  const int wm = w >> 1, wn = w & 1;
  const int m16 = lane & 15, q = lane >> 4;

  f32x4 acc[4][8];
  const f32x4 zero = {0.f, 0.f, 0.f, 0.f};
#pragma unroll
  for (int i = 0; i < 4; i++)
#pragma unroll
    for (int j = 0; j < 8; j++) acc[i][j] = zero;

  int arow = rowBase + srow;
  if (arow >= M) arow = M - 1;
  const float* aptr = A + (size_t)arow * K;
  const us* bptr = Bt + (size_t)t * K;

  for (int k0 = 0; k0 < K; k0 += 32) {
    const float* ap = aptr + k0 + sk;
    float4 x0 = ((const float4*)ap)[0];
    float4 x1 = ((const float4*)ap)[1];
    float4 x2 = ((const float4*)ap)[2];
    float4 x3 = ((const float4*)ap)[3];
    uint4 p0, p1;
    p0.x = (unsigned)f2bf(x0.x) | ((unsigned)f2bf(x0.y) << 16);
    p0.y = (unsigned)f2bf(x0.z) | ((unsigned)f2bf(x0.w) << 16);
    p0.z = (unsigned)f2bf(x1.x) | ((unsigned)f2bf(x1.y) << 16);
    p0.w = (unsigned)f2bf(x1.z) | ((unsigned)f2bf(x1.w) << 16);
    p1.x = (unsigned)f2bf(x2.x) | ((unsigned)f2bf(x2.y) << 16);
    p1.y = (unsigned)f2bf(x2.z) | ((unsigned)f2bf(x2.w) << 16);
    p1.z = (unsigned)f2bf(x3.x) | ((unsigned)f2bf(x3.y) << 16);
    p1.w = (unsigned)f2bf(x3.z) | ((unsigned)f2bf(x3.w) << 16);
    uint4 b0 = ((const uint4*)(bptr + k0))[0];
    uint4 b1 = ((const uint4*)(bptr + k0))[1];
    uint4 b2 = ((const uint4*)(bptr + k0))[2];
    uint4 b3 = ((const uint4*)(bptr + k0))[3];
    ((uint4*)&As[srow * 40 + sk])[0] = p0;
    ((uint4*)&As[srow * 40 + sk])[1] = p1;
    ((uint4*)&Bs[t * 40])[0] = b0;
    ((uint4*)&Bs[t * 40])[1] = b1;
    ((uint4*)&Bs[t * 40])[2] = b2;
    ((uint4*)&Bs[t * 40])[3] = b3;
    __syncthreads();
    s16x8 af[4], bfr[8];
#pragma unroll
    for (int mi = 0; mi < 4; mi++)
      af[mi] = *(const s16x8*)&As[(wm * 64 + mi * 16 + m16) * 40 + q * 8];
#pragma unroll
    for (int ni = 0; ni < 8; ni++)
      bfr[ni] = *(const s16x8*)&Bs[(wn * 128 + ni * 16 + m16) * 40 + q * 8];
#pragma unroll
    for (int mi = 0; mi < 4; mi++)
#pragma unroll
      for (int ni = 0; ni < 8; ni++)
        acc[mi][ni] = __builtin_amdgcn_mfma_f32_16x16x32_bf16(af[mi], bfr[ni], acc[mi][ni], 0, 0, 0);
    __syncthreads();
  }

#pragma unroll
  for (int ni = 0; ni < 8; ni++) {
    int col = wn * 128 + ni * 16 + m16;
    float bcol = bias[col];
#pragma unroll
    for (int mi = 0; mi < 4; mi++) {
#pragma unroll
      for (int r = 0; r < 4; r++) {
        int row = rowBase + wm * 64 + mi * 16 + q * 4 + r;
        if (row < M) C[(size_t)row * 256 + col] = f2bf(acc[mi][ni][r] + bcol);
      }
    }
  }
}

// ------- 8 GAT feature GEMMs in one dispatch: z=2g+j (j=0: fs via Ws, j=1: fd via Wd); K=256,Nn=128 -------
__global__ __launch_bounds__(256) void gat_gemm8_k(
    const us* __restrict__ ha, const us* __restrict__ ht,
    const us* __restrict__ gWst, const us* __restrict__ gWdt,
    const float* __restrict__ gbs, const float* __restrict__ gbd,
    us* __restrict__ fs_all, int M)
{
  __shared__ us As[128 * 40];
  __shared__ us Bs[128 * 40];
  const int z = blockIdx.z, g = z >> 1, j = z & 1;
  const us* A = (((j ? 0xC : 0x6) >> g) & 1) ? ht : ha;
  const us* Bt = (j ? gWdt : gWst) + ((size_t)g << 15);
  const float* bias = (j ? gbd : gbs) + g * 128;
  us* C = fs_all + (size_t)z * M * 128;

  const int t = threadIdx.x;
  const int rowBase = blockIdx.y * 128;
  const int srow = t >> 1, sk = (t & 1) * 16;
  const int w = t >> 6, lane = t & 63;
  const int wm = w >> 1, wn = w & 1;
  const int m16 = lane & 15, q = lane >> 4;

  f32x4 acc[4][4];
  const f32x4 zero = {0.f, 0.f, 0.f, 0.f};
#pragma unroll
  for (int i = 0; i < 4; i++)
#pragma unroll
    for (int jj = 0; jj < 4; jj++) acc[i][jj] = zero;

  int arow = rowBase + srow;
  if (arow >= M) arow = M - 1;
  const us* aptr = A + (size_t)arow * 256;
  const us* bptr = Bt + (size_t)srow * 256;

  for (int k0 = 0; k0 < 256; k0 += 32) {
    uint4 a0 = ((const uint4*)(aptr + k0 + sk))[0];
    uint4 a1 = ((const uint4*)(aptr + k0 + sk))[1];
    uint4 b0 = ((const uint4*)(bptr + k0 + sk))[0];
    uint4 b1 = ((const uint4*)(bptr + k0 + sk))[1];
    ((uint4*)&As[srow * 40 + sk])[0] = a0;
    ((uint4*)&As[srow * 40 + sk])[1] = a1;
    ((uint4*)&Bs[srow * 40 + sk])[0] = b0;
    ((uint4*)&Bs[srow * 40 + sk])[1] = b1;
    __syncthreads();
    s16x8 af[4], bfr[4];
#pragma unroll
    for (int mi = 0; mi < 4; mi++)
      af[mi] = *(const s16x8*)&As[(wm * 64 + mi * 16 + m16) * 40 + q * 8];
#pragma unroll
    for (int ni = 0; ni < 4; ni++)
      bfr[ni] = *(const s16x8*)&Bs[(wn * 64 + ni * 16 + m16) * 40 + q * 8];
#pragma unroll
    for (int mi = 0; mi < 4; mi++)
#pragma unroll
      for (int ni = 0; ni < 4; ni++)
        acc[mi][ni] = __builtin_amdgcn_mfma_f32_16x16x32_bf16(af[mi], bfr[ni], acc[mi][ni], 0, 0, 0);
    __syncthreads();
  }

#pragma unroll
  for (int ni = 0; ni < 4; ni++) {
    int col = wn * 64 + ni * 16 + m16;
    float bcol = bias[col];
#pragma unroll
    for (int mi = 0; mi < 4; mi++) {
#pragma unroll
      for (int r = 0; r < 4; r++) {
        int row = rowBase + wm * 64 + mi * 16 + q * 4 + r;
        if (row < M) C[(size_t)row * 128 + col] = f2bf(acc[mi][ni][r] + bcol);
      }
    }
  }
}

// ---------------- CSR build over 4 graphs concatenated ----------------
__global__ __launch_bounds__(256) void hist4_k(
    const int* __restrict__ e_aa, const int* __restrict__ e_ta,
    const int* __restrict__ e_tt, const int* __restrict__ e_at,
    int* __restrict__ cnt4)
{
  int g = blockIdx.z;
  const int* e = g == 0 ? e_aa : g == 1 ? e_ta : g == 2 ? e_tt : e_at;
  const int* dst = e + E_EDGES;
  int i = blockIdx.x * 256 + threadIdx.x;
  if (i < E_EDGES) atomicAdd(&cnt4[g * N_NODES + dst[i]], 1);
}

__global__ __launch_bounds__(1024) void scan1_k(const int* __restrict__ in, int* __restrict__ excl,
                                                int* __restrict__ bsums, int n) {
  __shared__ int tmp[1024];
  int gid = blockIdx.x * 1024 + threadIdx.x;
  int v = (gid < n) ? in[gid] : 0;
  tmp[threadIdx.x] = v;
  __syncthreads();
  int x = v;
  for (int d = 1; d < 1024; d <<= 1) {
    int y = (threadIdx.x >= d) ? tmp[threadIdx.x - d] : 0;
    __syncthreads();
    x += y;
    tmp[threadIdx.x] = x;
    __syncthreads();
  }
  if (gid < n) excl[gid] = x - v;
  if (threadIdx.x == 1023) bsums[blockIdx.x] = x;
}

__global__ __launch_bounds__(256) void scan2_k(const int* __restrict__ bsums, int* __restrict__ bbase, int nb) {
  __shared__ int tmp[256];
  int t = threadIdx.x;
  int v = (t < nb) ? bsums[t] : 0;
  tmp[t] = v;
  __syncthreads();
  int x = v;
  for (int d = 1; d < 256; d <<= 1) {
    int y = (t >= d) ? tmp[t - d] : 0;
    __syncthreads();
    x += y;
    tmp[t] = x;
    __syncthreads();
  }
  if (t < nb) bbase[t] = x - v;
}

__global__ __launch_bounds__(1024) void scan3_k(const int* __restrict__ excl, const int* __restrict__ bbase,
                                                int* __restrict__ offsets, int* __restrict__ cursor,
                                                int n, int e) {
  int gid = blockIdx.x * 1024 + threadIdx.x;
  if (gid < n) {
    int o = excl[gid] + bbase[blockIdx.x];
    offsets[gid] = o;
    cursor[gid] = o;
  }
  if (gid == 0) offsets[n] = e;
}

__global__ __launch_bounds__(256) void scatter4_k(
    const int* __restrict__ e_aa, const int* __restrict__ e_ta,
    const int* __restrict__ e_tt, const int* __restrict__ e_at,
    int* __restrict__ cursor4, int* __restrict__ esrc_all)
{
  int g = blockIdx.z;
  const int* e = g == 0 ? e_aa : g == 1 ? e_ta : g == 2 ? e_tt : e_at;
  const int* src = e;
  const int* dst = e + E_EDGES;
  int i = blockIdx.x * 256 + threadIdx.x;
  if (i < E_EDGES) {
    int p = atomicAdd(&cursor4[g * N_NODES + dst[i]], 1);
    esrc_all[p] = src[i];
  }
}

// -------- GATv2 edge-softmax + aggregate, all 4 graphs (z=graph); one wave per dst node --------
// Wave = 4 edge-slots x 16 feature-lanes (8 features / lane, uint4 = 16B gather per lane).
// 4 gathers in flight per wave instead of 1; head-dot reduce needs only xor 1,2 (head = 4 lanes).
__global__ __launch_bounds__(256) void aggregate4_k(
    const us* __restrict__ fs_all, const float* __restrict__ gattn,
    const int* __restrict__ offs4, const int* __restrict__ esrc_all,
    us* __restrict__ zb_all, int n)
{
  int g = blockIdx.z;
  const us* fs = fs_all + (size_t)(2 * g) * n * 128;
  const us* fd = fs_all + (size_t)(2 * g + 1) * n * 128;
  const float* attn = gattn + g * 128;
  us* zout = zb_all + (size_t)g * n * 128;
  const int* offs = offs4 + (size_t)g * n;

  int node = blockIdx.x * 4 + (threadIdx.x >> 6);
  int lane = threadIdx.x & 63;
  int slot = lane >> 4;   // 0..3 edge slot
  int sl = lane & 15;     // features sl*8 .. sl*8+7  (head = sl>>2)
  if (node >= n) return;

  uint4 fdu = *(const uint4*)(fd + (size_t)node * 128 + sl * 8);
  float fdv[8];
  fdv[0] = bflo(fdu.x); fdv[1] = bfhi(fdu.x);
  fdv[2] = bflo(fdu.y); fdv[3] = bfhi(fdu.y);
  fdv[4] = bflo(fdu.z); fdv[5] = bfhi(fdu.z);
  fdv[6] = bflo(fdu.w); fdv[7] = bfhi(fdu.w);
  float4 at0 = *(const float4*)(attn + sl * 8);
  float4 at1 = *(const float4*)(attn + sl * 8 + 4);
  float atv[8] = {at0.x, at0.y, at0.z, at0.w, at1.x, at1.y, at1.z, at1.w};

  int s0 = offs[node], s1 = offs[node + 1];
  float acc[8] = {0.f, 0.f, 0.f, 0.f, 0.f, 0.f, 0.f, 0.f};
  float sacc = 0.f;

  int i = s0 + slot;
  int src = (i < s1) ? esrc_all[i] : 0;
  while (i < s1) {
    int ni = i + 4;
    int nsrc = (ni < s1) ? esrc_all[ni] : 0;   // prefetch next index (breaks idx->gather chain)
    uint4 fu = *(const uint4*)(fs + (size_t)src * 128 + sl * 8);
    float fv[8];
    fv[0] = bflo(fu.x); fv[1] = bfhi(fu.x);
    fv[2] = bflo(fu.y); fv[3] = bfhi(fu.y);
    fv[4] = bflo(fu.z); fv[5] = bfhi(fu.z);
    fv[6] = bflo(fu.w); fv[7] = bfhi(fu.w);
    float p = 0.f;
#pragma unroll
    for (int j = 0; j < 8; j++) {
      float tt = fv[j] + fdv[j];
      tt = (tt > 0.f) ? tt : 0.2f * tt;
      p += tt * atv[j];
    }
    p += __shfl_xor(p, 1);
    p += __shfl_xor(p, 2);     // full 32-elem head dot (4 lanes x 8)
    float ex = __expf(p);
    sacc += ex;
#pragma unroll
    for (int j = 0; j < 8; j++) acc[j] += ex * fv[j];
    i = ni;
    src = nsrc;
  }

  // combine the 4 slot partials
#pragma unroll
  for (int j = 0; j < 8; j++) {
    acc[j] += __shfl_xor(acc[j], 16);
    acc[j] += __shfl_xor(acc[j], 32);
  }
  sacc += __shfl_xor(sacc, 16);
  sacc += __shfl_xor(sacc, 32);

  if (slot == 0) {
    float inv = (s1 > s0) ? (1.f / sacc) : 0.f;
    uint4 o;
    o.x = (unsigned)f2bf(fmaxf(acc[0] * inv, 0.f)) | ((unsigned)f2bf(fmaxf(acc[1] * inv, 0.f)) << 16);
    o.y = (unsigned)f2bf(fmaxf(acc[2] * inv, 0.f)) | ((unsigned)f2bf(fmaxf(acc[3] * inv, 0.f)) << 16);
    o.z = (unsigned)f2bf(fmaxf(acc[4] * inv, 0.f)) | ((unsigned)f2bf(fmaxf(acc[5] * inv, 0.f)) << 16);
    o.w = (unsigned)f2bf(fmaxf(acc[6] * inv, 0.f)) | ((unsigned)f2bf(fmaxf(acc[7] * inv, 0.f)) << 16);
    *(uint4*)(zout + (size_t)node * 128 + sl * 8) = o;
  }
}

// ---------------- semantic attention, MFMA-fused ----------------
__global__ __launch_bounds__(256) void satt_mfma_k(
    const us* __restrict__ z0, const us* __restrict__ z1,
    const us* __restrict__ Wat, const float* __restrict__ ba,
    const float* __restrict__ Wo, float* __restrict__ w_acc, int M)
{
  __shared__ us As[128 * 40];
  __shared__ us Bs[128 * 40];
  const us* Z = blockIdx.z ? z1 : z0;
  const int t = threadIdx.x;
  const int rowBase = blockIdx.y * 128;
  const int srow = t >> 1, sk = (t & 1) * 16;
  const int w = t >> 6, lane = t & 63;
  const int wm = w >> 1, wn = w & 1;
  const int m16 = lane & 15, q = lane >> 4;

  f32x4 acc[4][4];
  const f32x4 zero = {0.f, 0.f, 0.f, 0.f};
#pragma unroll
  for (int i = 0; i < 4; i++)
#pragma unroll
    for (int j = 0; j < 4; j++) acc[i][j] = zero;

  int arow = rowBase + srow;
  if (arow >= M) arow = M - 1;
  const us* aptr = Z + (size_t)arow * 128;
  const us* bptr = Wat + (size_t)srow * 128;

  for (int k0 = 0; k0 < 128; k0 += 32) {
    uint4 a0 = ((const uint4*)(aptr + k0 + sk))[0];
    uint4 a1 = ((const uint4*)(aptr + k0 + sk))[1];
    uint4 b0 = ((const uint4*)(bptr + k0 + sk))[0];
    uint4 b1 = ((const uint4*)(bptr + k0 + sk))[1];
    ((uint4*)&As[srow * 40 + sk])[0] = a0;
    ((uint4*)&As[srow * 40 + sk])[1] = a1;
    ((uint4*)&Bs[srow * 40 + sk])[0] = b0;
    ((uint4*)&Bs[srow * 40 + sk])[1] = b1;
    __syncthreads();
    s16x8 af[4], bfr[4];
#pragma unroll
    for (int mi = 0; mi < 4; mi++)
      af[mi] = *(const s16x8*)&As[(wm * 64 + mi * 16 + m16) * 40 + q * 8];
#pragma unroll
    for (int ni = 0; ni < 4; ni++)
      bfr[ni] = *(const s16x8*)&Bs[(wn * 64 + ni * 16 + m16) * 40 + q * 8];
#pragma unroll
    for (int mi = 0; mi < 4; mi++)
#pragma unroll
      for (int ni = 0; ni < 4; ni++)
        acc[mi][ni] = __builtin_amdgcn_mfma_f32_16x16x32_bf16(af[mi], bfr[ni], acc[mi][ni], 0, 0, 0);
    __syncthreads();
  }

  float s = 0.f;
#pragma unroll
  for (int ni = 0; ni < 4; ni++) {
    int col = wn * 64 + ni * 16 + m16;
    float bcol = ba[col], wcol = Wo[col];
#pragma unroll
    for (int mi = 0; mi < 4; mi++) {
#pragma unroll
      for (int r = 0; r < 4; r++) {
        int row = rowBase + wm * 64 + mi * 16 + q * 4 + r;
        if (row < M) s += tanhf(acc[mi][ni][r] + bcol) * wcol;
      }
    }
  }
  for (int d = 1; d < 64; d <<= 1) s += __shfl_xor(s, d);
  __shared__ float red[4];
  if (lane == 0) red[w] = s;
  __syncthreads();
  if (t == 0) atomicAdd(&w_acc[blockIdx.z], red[0] + red[1] + red[2] + red[3]);
}

__global__ void beta_k(const float* __restrict__ w_acc, float* __restrict__ beta, float invn) {
  if (threadIdx.x == 0 && blockIdx.x == 0) {
    float w0 = w_acc[0] * invn, w1 = w_acc[1] * invn;
    float m = fmaxf(w0, w1);
    float e0 = expf(w0 - m), e1 = expf(w1 - m);
    float s = e0 + e1;
    beta[0] = e0 / s; beta[1] = e1 / s;
    float w2 = w_acc[2] * invn, w3 = w_acc[3] * invn;
    float m2 = fmaxf(w2, w3);
    float e2 = expf(w2 - m2), e3 = expf(w3 - m2);
    float s2 = e2 + e3;
    beta[2] = e2 / s2; beta[3] = e3 / s2;
  }
}

static __device__ __forceinline__ unsigned int comb2(unsigned int a, unsigned int b, float b0, float b1) {
  float lo = bflo(a) * b0 + bflo(b) * b1;
  float hi = bfhi(a) * b0 + bfhi(b) * b1;
  return (unsigned int)f2bf(lo) | ((unsigned int)f2bf(hi) << 16);
}

__global__ __launch_bounds__(256) void combine2_k(const us* __restrict__ zb_all,
                                                  const float* __restrict__ beta,
                                                  us* __restrict__ haob, us* __restrict__ htob, int n8) {
  int z = blockIdx.z;
  const us* za = zb_all + (size_t)(2 * z) * N_NODES * 128;
  const us* zbv = zb_all + (size_t)(2 * z + 1) * N_NODES * 128;
  float b0 = beta[2 * z], b1 = beta[2 * z + 1];
  us* outv = z ? htob : haob;
  for (int i = blockIdx.x * 256 + threadIdx.x; i < n8; i += gridDim.x * 256) {
    uint4 a = ((const uint4*)za)[i];
    uint4 b = ((const uint4*)zbv)[i];
    uint4 o;
    o.x = comb2(a.x, b.x, b0, b1);
    o.y = comb2(a.y, b.y, b0, b1);
    o.z = comb2(a.z, b.z, b0, b1);
    o.w = comb2(a.w, b.w, b0, b1);
    ((uint4*)outv)[i] = o;
  }
}

// -------- predictor fully fused: gather-concat GEMM(K=256,N=128) + relu + dot(W2) + sigmoid --------
// z = 0: pos edges, 1: neg edges. Block covers 128 edges; second layer reduced in-block.
__global__ __launch_bounds__(256) void pred_fused_k(
    const us* __restrict__ haob, const us* __restrict__ htob,
    const int* __restrict__ pos_e, const int* __restrict__ neg_e,
    const us* __restrict__ prW1t, const float* __restrict__ prb1,
    const float* __restrict__ prW2, const float* __restrict__ prb2,
    float* __restrict__ out, int M)
{
  __shared__ us As[128 * 40];
  __shared__ us Bs[128 * 40];
  const int z = blockIdx.z;
  const int* pe = z ? neg_e : pos_e;
  float* o = out + (size_t)z * M;

  const int t = threadIdx.x;
  const int rowBase = blockIdx.x * 128;
  const int srow = t >> 1, sk = (t & 1) * 16;
  const int w = t >> 6, lane = t & 63;
  const int wm = w >> 1, wn = w & 1;
  const int m16 = lane & 15, q = lane >> 4;

  f32x4 acc[4][4];
  const f32x4 zero = {0.f, 0.f, 0.f, 0.f};
#pragma unroll
  for (int i = 0; i < 4; i++)
#pragma unroll
    for (int j = 0; j < 4; j++) acc[i][j] = zero;

  int arow = rowBase + srow;
  if (arow >= M) arow = M - 1;
  const int srcn = pe[arow];
  const int dstn = pe[M + arow];
  const us* bptr = prW1t + (size_t)srow * 256;

  for (int k0 = 0; k0 < 256; k0 += 32) {
    const us* asrc = (k0 < 128) ? (haob + (size_t)srcn * 128 + k0 + sk)
                                : (htob + (size_t)dstn * 128 + (k0 - 128) + sk);
    uint4 a0 = ((const uint4*)asrc)[0];
    uint4 a1 = ((const uint4*)asrc)[1];
    uint4 b0 = ((const uint4*)(bptr + k0 + sk))[0];
    uint4 b1 = ((const uint4*)(bptr + k0 + sk))[1];
    ((uint4*)&As[srow * 40 + sk])[0] = a0;
    ((uint4*)&As[srow * 40 + sk])[1] = a1;
    ((uint4*)&Bs[srow * 40 + sk])[0] = b0;
    ((uint4*)&Bs[srow * 40 + sk])[1] = b1;
    __syncthreads();
    s16x8 af[4], bfr[4];
#pragma unroll
    for (int mi = 0; mi < 4; mi++)
      af[mi] = *(const s16x8*)&As[(wm * 64 + mi * 16 + m16) * 40 + q * 8];
#pragma unroll
    for (int ni = 0; ni < 4; ni++)
      bfr[ni] = *(const s16x8*)&Bs[(wn * 64 + ni * 16 + m16) * 40 + q * 8];
#pragma unroll
    for (int mi = 0; mi < 4; mi++)
#pragma unroll
      for (int ni = 0; ni < 4; ni++)
        acc[mi][ni] = __builtin_amdgcn_mfma_f32_16x16x32_bf16(af[mi], bfr[ni], acc[mi][ni], 0, 0, 0);
    __syncthreads();
  }

  // layer 2: per-row dot with prW2 after relu(+prb1)
  float* rsum = (float*)As;
  if (t < 128) rsum[t] = 0.f;
  __syncthreads();
  float bcol[4], w2c[4];
#pragma unroll
  for (int ni = 0; ni < 4; ni++) {
    int col = wn * 64 + ni * 16 + m16;
    bcol[ni] = prb1[col];
    w2c[ni] = prW2[col];
  }
#pragma unroll
  for (int mi = 0; mi < 4; mi++) {
#pragma unroll
    for (int r = 0; r < 4; r++) {
      float s = 0.f;
#pragma unroll
      for (int ni = 0; ni < 4; ni++)
        s += fmaxf(acc[mi][ni][r] + bcol[ni], 0.f) * w2c[ni];
      s += __shfl_xor(s, 1);
      s += __shfl_xor(s, 2);
      s += __shfl_xor(s, 4);
      s += __shfl_xor(s, 8);
      if (m16 == 0) atomicAdd(&rsum[wm * 64 + mi * 16 + q * 4 + r], s);
    }
  }
  __syncthreads();
  if (t < 128) {
    int row = rowBase + t;
    if (row < M) o[row] = 1.f / (1.f + expf(-(rsum[t] + prb2[0])));
  }
}

extern "C" void kernel_launch(void* const* d_in, const int* in_sizes, int n_in,
                              void* d_out, int out_size, void* d_ws, size_t ws_size,
                              hipStream_t stream) {
  const float* PE   = (const float*)d_in[0];
  const float* GE   = (const float*)d_in[1];
  const float* W1   = (const float*)d_in[2];
  const float* b1   = (const float*)d_in[3];
  const float* W2   = (const float*)d_in[4];
  const float* b2   = (const float*)d_in[5];
  const float* gWs  = (const float*)d_in[6];
  const float* gbs  = (const float*)d_in[7];
  const float* gWd  = (const float*)d_in[8];
  const float* gbd  = (const float*)d_in[9];
  const float* gattn= (const float*)d_in[10];
  const float* pW1  = (const float*)d_in[11];
  const float* pb1  = (const float*)d_in[12];
  const float* pW2  = (const float*)d_in[13];
  const float* gaW1 = (const float*)d_in[14];
  const float* gab1 = (const float*)d_in[15];
  const float* gaW2 = (const float*)d_in[16];
  const float* prW1 = (const float*)d_in[17];
  const float* prb1 = (const float*)d_in[18];
  const float* prW2 = (const float*)d_in[19];
  const float* prb2 = (const float*)d_in[20];
  const int* e_aa = (const int*)d_in[21];
  const int* e_ta = (const int*)d_in[22];
  const int* e_tt = (const int*)d_in[23];
  const int* e_at = (const int*)d_in[24];
  const int* pos_e = (const int*)d_in[25];
  const int* neg_e = (const int*)d_in[26];
  float* out = (float*)d_out;

  // ---- workspace layout ----
  us* usws = (us*)d_ws;
  size_t o = 0;
  us* ha_b   = usws + o; o += (size_t)N_NODES * 256;   // 12.8M
  us* ht_b   = usws + o; o += (size_t)N_NODES * 256;
  us* fs_all = usws + o; o += (size_t)8 * N_NODES * 128; // 51.2M
  us* zb_all = usws + o; o += (size_t)4 * N_NODES * 128; // 25.6M
  us* haob   = usws + o; o += (size_t)N_NODES * 128;
  us* htob   = usws + o; o += (size_t)N_NODES * 128;
  us* W2t    = usws + o; o += 262144;
  us* W1t    = usws + o; o += 131072;
  us* gWst   = usws + o; o += 131072;
  us* gWdt   = usws + o; o += 131072;
  us* prW1t  = usws + o; o += 32768;
  us* WaPt   = usws + o; o += 16384;
  us* WaGt   = usws + o; o += 16384;
  float* w_acc = (float*)(usws + o); o += 16;
  float* beta  = w_acc + 4;
  int* ib = (int*)(usws + o);
  size_t io = 0;
  int* cnt4    = ib + io; io += NG4;
  int* excl    = ib + io; io += NG4;
  int* bsums   = ib + io; io += 256;
  int* bbase   = ib + io; io += 256;
  int* offs4   = ib + io; io += NG4 + 4;
  int* cursor4 = ib + io; io += NG4;
  int* esrc    = ib + io; io += ETOT;

  const int SCAN_B = idiv(NG4, 1024);  // 196
  dim3 blk256(256), blk1024(1024);
  const int MT = idiv(N_NODES, 128);   // 391
  const int ET = idiv(EP_EDGES, 128);  // 1563

  // 1) weights
  wtrans_all_k<<<dim3(64, 1, 7), blk256, 0, stream>>>(
      W2, W1, gWs, gWd, prW1, pW1, gaW1, W2t, W1t, gWst, gWdt, prW1t, WaPt, WaGt);

  // 2-3) input projections (fused fp32->bf16, full-width 256-col tile)
  proj_gemm_k<<<dim3(MT), blk256, 0, stream>>>(PE, W2t, b2, ha_b, N_NODES, 1024);
  proj_gemm_k<<<dim3(MT), blk256, 0, stream>>>(GE, W1t, b1, ht_b, N_NODES, 512);

  // 4) all 8 GAT feature GEMMs
  gat_gemm8_k<<<dim3(1, MT, 8), blk256, 0, stream>>>(ha_b, ht_b, gWst, gWdt, gbs, gbd, fs_all, N_NODES);

  // 5-10) CSR build for all 4 graphs at once
  hipMemsetAsync(cnt4, 0, NG4 * sizeof(int), stream);
  hist4_k<<<dim3(idiv(E_EDGES, 256), 1, 4), blk256, 0, stream>>>(e_aa, e_ta, e_tt, e_at, cnt4);
  scan1_k<<<SCAN_B, blk1024, 0, stream>>>(cnt4, excl, bsums, NG4);
  scan2_k<<<1, blk256, 0, stream>>>(bsums, bbase, SCAN_B);
  scan3_k<<<SCAN_B, blk1024, 0, stream>>>(excl, bbase, offs4, cursor4, NG4, ETOT);
  scatter4_k<<<dim3(idiv(E_EDGES, 256), 1, 4), blk256, 0, stream>>>(e_aa, e_ta, e_tt, e_at, cursor4, esrc);

  // 11) all 4 edge-softmax aggregations
  aggregate4_k<<<dim3(idiv(N_NODES, 4), 1, 4), blk256, 0, stream>>>(fs_all, gattn, offs4, esrc, zb_all, N_NODES);

  // 12-13) semantic attention
  hipMemsetAsync(w_acc, 0, 4 * sizeof(float), stream);
  satt_mfma_k<<<dim3(1, MT, 2), blk256, 0, stream>>>(
      zb_all, zb_all + (size_t)N_NODES * 128, WaPt, pb1, pW2, w_acc + 0, N_NODES);
  satt_mfma_k<<<dim3(1, MT, 2), blk256, 0, stream>>>(
      zb_all + (size_t)2 * N_NODES * 128, zb_all + (size_t)3 * N_NODES * 128, WaGt, gab1, gaW2, w_acc + 2, N_NODES);
  beta_k<<<1, 64, 0, stream>>>(w_acc, beta, 1.0f / (float)N_NODES);

  // 14) combine both groups
  combine2_k<<<dim3(2048, 1, 2), blk256, 0, stream>>>(zb_all, beta, haob, htob, N_NODES * 128 / 8);

  // 15) fully fused predictor (pos+neg)
  pred_fused_k<<<dim3(ET, 1, 2), blk256, 0, stream>>>(
      haob, htob, pos_e, neg_e, prW1t, prb1, prW2, prb2, out, EP_EDGES);
}

// Round 2
// 1067.056 us; speedup vs baseline: 1.4615x; 1.2868x over previous
//
#include <hip/hip_runtime.h>
#include <math.h>

#define N_NODES 50000
#define E_EDGES 800000
#define EP_EDGES 200000
#define NG4 (4 * N_NODES)
#define ETOT (4 * E_EDGES)
#define NBUCK 196   // ceil(50000/256)

static inline int idiv(int a, int b) { return (a + b - 1) / b; }

typedef short s16x8 __attribute__((ext_vector_type(8)));
typedef float f32x4 __attribute__((ext_vector_type(4)));
typedef unsigned short us;

static __device__ __forceinline__ us f2bf(float f) {
  unsigned int u = __float_as_uint(f);
  u += 0x7FFFu + ((u >> 16) & 1u);
  return (us)(u >> 16);
}
static __device__ __forceinline__ float bflo(unsigned int u) { return __uint_as_float(u << 16); }
static __device__ __forceinline__ float bfhi(unsigned int u) { return __uint_as_float(u & 0xffff0000u); }

// ---------------- fused weight transpose+convert: 7 segments via blockIdx.z ----------------
__global__ __launch_bounds__(256) void wtrans_all_k(
    const float* __restrict__ W2, const float* __restrict__ W1,
    const float* __restrict__ gWs, const float* __restrict__ gWd,
    const float* __restrict__ prW1, const float* __restrict__ pW1,
    const float* __restrict__ gaW1,
    us* __restrict__ W2t, us* __restrict__ W1t, us* __restrict__ gWst,
    us* __restrict__ gWdt, us* __restrict__ prW1t, us* __restrict__ WaPt,
    us* __restrict__ WaGt)
{
  const float* src; us* dst; int ks, nsh, total;
  switch (blockIdx.z) {
    case 0: src = W2;   dst = W2t;   ks = 10; nsh = 8; total = 262144; break;
    case 1: src = W1;   dst = W1t;   ks = 9;  nsh = 8; total = 131072; break;
    case 2: src = gWs;  dst = gWst;  ks = 8;  nsh = 7; total = 131072; break;
    case 3: src = gWd;  dst = gWdt;  ks = 8;  nsh = 7; total = 131072; break;
    case 4: src = prW1; dst = prW1t; ks = 8;  nsh = 7; total = 32768;  break;
    case 5: src = pW1;  dst = WaPt;  ks = 7;  nsh = 7; total = 16384;  break;
    default: src = gaW1; dst = WaGt; ks = 7;  nsh = 7; total = 16384;  break;
  }
  int psh = ks + nsh;
  int Km1 = (1 << ks) - 1;
  int pm1 = (1 << psh) - 1;
  for (int gid = blockIdx.x * 256 + threadIdx.x; gid < total; gid += gridDim.x * 256) {
    int mat = gid >> psh;
    int rem = gid & pm1;
    int n = rem >> ks, k = rem & Km1;
    dst[gid] = f2bf(src[((size_t)mat << psh) + ((size_t)k << nsh) + n]);
  }
}

// ------- projection GEMM with fused f32->bf16 A conversion: C[M,256] = bf16(A[M,K]) @ Bt^T + bias -------
__global__ __launch_bounds__(256) void proj_gemm_k(
    const float* __restrict__ A, const us* __restrict__ Bt,
    const float* __restrict__ bias, us* __restrict__ C, int M, int K)
{
  __shared__ us As[128 * 40];
  __shared__ us Bs[256 * 40];
  const int t = threadIdx.x;
  const int rowBase = blockIdx.x * 128;
  const int srow = t >> 1, sk = (t & 1) * 16;
  const int w = t >> 6, lane = t & 63;
  const int wm = w >> 1, wn = w & 1;
  const int m16 = lane & 15, q = lane >> 4;

  f32x4 acc[4][8];
  const f32x4 zero = {0.f, 0.f, 0.f, 0.f};
#pragma unroll
  for (int i = 0; i < 4; i++)
#pragma unroll
    for (int j = 0; j < 8; j++) acc[i][j] = zero;

  int arow = rowBase + srow;
  if (arow >= M) arow = M - 1;
  const float* aptr = A + (size_t)arow * K;
  const us* bptr = Bt + (size_t)t * K;

  for (int k0 = 0; k0 < K; k0 += 32) {
    const float* ap = aptr + k0 + sk;
    float4 x0 = ((const float4*)ap)[0];
    float4 x1 = ((const float4*)ap)[1];
    float4 x2 = ((const float4*)ap)[2];
    float4 x3 = ((const float4*)ap)[3];
    uint4 p0, p1;
    p0.x = (unsigned)f2bf(x0.x) | ((unsigned)f2bf(x0.y) << 16);
    p0.y = (unsigned)f2bf(x0.z) | ((unsigned)f2bf(x0.w) << 16);
    p0.z = (unsigned)f2bf(x1.x) | ((unsigned)f2bf(x1.y) << 16);
    p0.w = (unsigned)f2bf(x1.z) | ((unsigned)f2bf(x1.w) << 16);
    p1.x = (unsigned)f2bf(x2.x) | ((unsigned)f2bf(x2.y) << 16);
    p1.y = (unsigned)f2bf(x2.z) | ((unsigned)f2bf(x2.w) << 16);
    p1.z = (unsigned)f2bf(x3.x) | ((unsigned)f2bf(x3.y) << 16);
    p1.w = (unsigned)f2bf(x3.z) | ((unsigned)f2bf(x3.w) << 16);
    uint4 b0 = ((const uint4*)(bptr + k0))[0];
    uint4 b1 = ((const uint4*)(bptr + k0))[1];
    uint4 b2 = ((const uint4*)(bptr + k0))[2];
    uint4 b3 = ((const uint4*)(bptr + k0))[3];
    ((uint4*)&As[srow * 40 + sk])[0] = p0;
    ((uint4*)&As[srow * 40 + sk])[1] = p1;
    ((uint4*)&Bs[t * 40])[0] = b0;
    ((uint4*)&Bs[t * 40])[1] = b1;
    ((uint4*)&Bs[t * 40])[2] = b2;
    ((uint4*)&Bs[t * 40])[3] = b3;
    __syncthreads();
    s16x8 af[4], bfr[8];
#pragma unroll
    for (int mi = 0; mi < 4; mi++)
      af[mi] = *(const s16x8*)&As[(wm * 64 + mi * 16 + m16) * 40 + q * 8];
#pragma unroll
    for (int ni = 0; ni < 8; ni++)
      bfr[ni] = *(const s16x8*)&Bs[(wn * 128 + ni * 16 + m16) * 40 + q * 8];
#pragma unroll
    for (int mi = 0; mi < 4; mi++)
#pragma unroll
      for (int ni = 0; ni < 8; ni++)
        acc[mi][ni] = __builtin_amdgcn_mfma_f32_16x16x32_bf16(af[mi], bfr[ni], acc[mi][ni], 0, 0, 0);
    __syncthreads();
  }

#pragma unroll
  for (int ni = 0; ni < 8; ni++) {
    int col = wn * 128 + ni * 16 + m16;
    float bcol = bias[col];
#pragma unroll
    for (int mi = 0; mi < 4; mi++) {
#pragma unroll
      for (int r = 0; r < 4; r++) {
        int row = rowBase + wm * 64 + mi * 16 + q * 4 + r;
        if (row < M) C[(size_t)row * 256 + col] = f2bf(acc[mi][ni][r] + bcol);
      }
    }
  }
}

// ------- 8 GAT feature GEMMs in one dispatch -------
__global__ __launch_bounds__(256) void gat_gemm8_k(
    const us* __restrict__ ha, const us* __restrict__ ht,
    const us* __restrict__ gWst, const us* __restrict__ gWdt,
    const float* __restrict__ gbs, const float* __restrict__ gbd,
    us* __restrict__ fs_all, int M)
{
  __shared__ us As[128 * 40];
  __shared__ us Bs[128 * 40];
  const int z = blockIdx.z, g = z >> 1, j = z & 1;
  const us* A = (((j ? 0xC : 0x6) >> g) & 1) ? ht : ha;
  const us* Bt = (j ? gWdt : gWst) + ((size_t)g << 15);
  const float* bias = (j ? gbd : gbs) + g * 128;
  us* C = fs_all + (size_t)z * M * 128;

  const int t = threadIdx.x;
  const int rowBase = blockIdx.y * 128;
  const int srow = t >> 1, sk = (t & 1) * 16;
  const int w = t >> 6, lane = t & 63;
  const int wm = w >> 1, wn = w & 1;
  const int m16 = lane & 15, q = lane >> 4;

  f32x4 acc[4][4];
  const f32x4 zero = {0.f, 0.f, 0.f, 0.f};
#pragma unroll
  for (int i = 0; i < 4; i++)
#pragma unroll
    for (int jj = 0; jj < 4; jj++) acc[i][jj] = zero;

  int arow = rowBase + srow;
  if (arow >= M) arow = M - 1;
  const us* aptr = A + (size_t)arow * 256;
  const us* bptr = Bt + (size_t)srow * 256;

  for (int k0 = 0; k0 < 256; k0 += 32) {
    uint4 a0 = ((const uint4*)(aptr + k0 + sk))[0];
    uint4 a1 = ((const uint4*)(aptr + k0 + sk))[1];
    uint4 b0 = ((const uint4*)(bptr + k0 + sk))[0];
    uint4 b1 = ((const uint4*)(bptr + k0 + sk))[1];
    ((uint4*)&As[srow * 40 + sk])[0] = a0;
    ((uint4*)&As[srow * 40 + sk])[1] = a1;
    ((uint4*)&Bs[srow * 40 + sk])[0] = b0;
    ((uint4*)&Bs[srow * 40 + sk])[1] = b1;
    __syncthreads();
    s16x8 af[4], bfr[4];
#pragma unroll
    for (int mi = 0; mi < 4; mi++)
      af[mi] = *(const s16x8*)&As[(wm * 64 + mi * 16 + m16) * 40 + q * 8];
#pragma unroll
    for (int ni = 0; ni < 4; ni++)
      bfr[ni] = *(const s16x8*)&Bs[(wn * 64 + ni * 16 + m16) * 40 + q * 8];
#pragma unroll
    for (int mi = 0; mi < 4; mi++)
#pragma unroll
      for (int ni = 0; ni < 4; ni++)
        acc[mi][ni] = __builtin_amdgcn_mfma_f32_16x16x32_bf16(af[mi], bfr[ni], acc[mi][ni], 0, 0, 0);
    __syncthreads();
  }

#pragma unroll
  for (int ni = 0; ni < 4; ni++) {
    int col = wn * 64 + ni * 16 + m16;
    float bcol = bias[col];
#pragma unroll
    for (int mi = 0; mi < 4; mi++) {
#pragma unroll
      for (int r = 0; r < 4; r++) {
        int row = rowBase + wm * 64 + mi * 16 + q * 4 + r;
        if (row < M) C[(size_t)row * 128 + col] = f2bf(acc[mi][ni][r] + bcol);
      }
    }
  }
}

// ---------------- CSR build v2: coarse-bucket two-phase (no 4B random scatter) ----------------
// Phase A: LDS-privatized bucket histogram (bucket = dst>>8, 196/graph)
__global__ __launch_bounds__(256) void bhist_k(
    const int* __restrict__ e_aa, const int* __restrict__ e_ta,
    const int* __restrict__ e_tt, const int* __restrict__ e_at,
    int* __restrict__ bhist)
{
  int g = blockIdx.z;
  const int* e = g == 0 ? e_aa : g == 1 ? e_ta : g == 2 ? e_tt : e_at;
  const int* dstp = e + E_EDGES;
  __shared__ int lh[256];
  int t = threadIdx.x;
  lh[t] = 0;
  __syncthreads();
  int base = blockIdx.x * 2048;
#pragma unroll
  for (int r = 0; r < 8; r++) {
    int i = base + r * 256 + t;
    if (i < E_EDGES) atomicAdd(&lh[dstp[i] >> 8], 1);
  }
  __syncthreads();
  if (t < NBUCK && lh[t]) atomicAdd(&bhist[g * NBUCK + t], lh[t]);
}

// Phase B: scan 784 bucket counts -> bases + cursors; sentinel at [784]
__global__ __launch_bounds__(1024) void bscan_k(const int* __restrict__ bhist,
                                                int* __restrict__ bbase, int* __restrict__ bcur) {
  __shared__ int tmp[1024];
  int t = threadIdx.x;
  int v = (t < 4 * NBUCK) ? bhist[t] : 0;
  tmp[t] = v;
  __syncthreads();
  int x = v;
  for (int d = 1; d < 1024; d <<= 1) {
    int y = (t >= d) ? tmp[t - d] : 0;
    __syncthreads();
    x += y;
    tmp[t] = x;
    __syncthreads();
  }
  if (t < 4 * NBUCK) {
    int e = x - v;
    bbase[t] = e;
    bcur[t] = e;
  }
  if (t == 4 * NBUCK - 1) bbase[4 * NBUCK] = x;  // = ETOT
}

// Phase C: LDS-binned scatter of packed (dst<<16|src) into bucket regions; writes are
// contiguous runs per bucket (avg ~21 edges), not 4B random.
__global__ __launch_bounds__(256) void binscatter_k(
    const int* __restrict__ e_aa, const int* __restrict__ e_ta,
    const int* __restrict__ e_tt, const int* __restrict__ e_at,
    int* __restrict__ bcur, unsigned int* __restrict__ epack)
{
  int g = blockIdx.z;
  const int* e = g == 0 ? e_aa : g == 1 ? e_ta : g == 2 ? e_tt : e_at;
  const int* srcp = e;
  const int* dstp = e + E_EDGES;
  const int base = blockIdx.x * 4096;
  const int cnt = min(4096, E_EDGES - base);
  __shared__ int lh[256], sc[256], lcur[256], gb[256];
  __shared__ unsigned int spack[4096];
  __shared__ unsigned short sbuck[4096];
  const int t = threadIdx.x;
  lh[t] = 0;
  __syncthreads();
  int ds[16], ss[16];
#pragma unroll
  for (int r = 0; r < 16; r++) {
    int i = r * 256 + t;
    if (i < cnt) {
      ds[r] = dstp[base + i];
      ss[r] = srcp[base + i];
      atomicAdd(&lh[ds[r] >> 8], 1);
    } else ds[r] = -1;
  }
  __syncthreads();
  int v = lh[t];
  sc[t] = v;
  __syncthreads();
  int x = v;
  for (int d = 1; d < 256; d <<= 1) {
    int y = (t >= d) ? sc[t - d] : 0;
    __syncthreads();
    x += y;
    sc[t] = x;
    __syncthreads();
  }
  lcur[t] = x - v;  // exclusive scan = local bucket start
  if (t < NBUCK) gb[t] = atomicAdd(&bcur[g * NBUCK + t], v);
  __syncthreads();
#pragma unroll
  for (int r = 0; r < 16; r++) {
    if (ds[r] >= 0) {
      int b = ds[r] >> 8;
      int rank = atomicAdd(&lcur[b], 1);
      spack[rank] = ((unsigned int)ds[r] << 16) | (unsigned int)ss[r];
      sbuck[rank] = (unsigned short)b;
    }
  }
  __syncthreads();
  for (int j = t; j < cnt; j += 256) {
    int b = sbuck[j];
    epack[gb[b] + (j - (sc[b] - lh[b]))] = spack[j];
  }
}

// Phase D: one block per (graph,bucket): per-dst hist+scan in LDS (emits offs4!),
// then final scatter within the bucket's ~16KB window (single-writer L2 locality).
__global__ __launch_bounds__(256) void bucketscatter2_k(
    const int* __restrict__ bbase, const unsigned int* __restrict__ epack,
    int* __restrict__ esrc_all, int* __restrict__ offs4)
{
  int g = blockIdx.z, b = blockIdx.x;
  int gb = g * NBUCK + b;
  int start = bbase[gb], end = bbase[gb + 1];
  int ndst = min(256, N_NODES - (b << 8));
  __shared__ int lh[256], cur[256];
  int t = threadIdx.x;
  lh[t] = 0;
  __syncthreads();
  for (int i = start + t; i < end; i += 256)
    atomicAdd(&lh[(epack[i] >> 16) & 255], 1);
  __syncthreads();
  int v = lh[t];
  cur[t] = v;
  __syncthreads();
  int x = v;
  for (int d = 1; d < 256; d <<= 1) {
    int y = (t >= d) ? cur[t - d] : 0;
    __syncthreads();
    x += y;
    cur[t] = x;
    __syncthreads();
  }
  int mybase = start + x - v;
  if (t < ndst) offs4[g * N_NODES + (b << 8) + t] = mybase;
  cur[t] = mybase;
  __syncthreads();
  if (gb == 4 * NBUCK - 1 && t == 0) offs4[NG4] = end;
  unsigned int pk = (start + t < end) ? epack[start + t] : 0u;
  for (int i = start + t; i < end; i += 256) {
    unsigned int nk = (i + 256 < end) ? epack[i + 256] : 0u;
    int dl = (pk >> 16) & 255;
    int pos = atomicAdd(&cur[dl], 1);
    esrc_all[pos] = (int)(pk & 0xffffu);
    pk = nk;
  }
}

// -------- GATv2 edge-softmax + aggregate, all 4 graphs (z=graph) --------
// Wave = 4 edge-slots x 16 feature-lanes (8 features / lane, uint4 = 16B gather per lane).
__global__ __launch_bounds__(256) void aggregate4_k(
    const us* __restrict__ fs_all, const float* __restrict__ gattn,
    const int* __restrict__ offs4, const int* __restrict__ esrc_all,
    us* __restrict__ zb_all, int n)
{
  int g = blockIdx.z;
  const us* fs = fs_all + (size_t)(2 * g) * n * 128;
  const us* fd = fs_all + (size_t)(2 * g + 1) * n * 128;
  const float* attn = gattn + g * 128;
  us* zout = zb_all + (size_t)g * n * 128;
  const int* offs = offs4 + (size_t)g * n;

  int node = blockIdx.x * 4 + (threadIdx.x >> 6);
  int lane = threadIdx.x & 63;
  int slot = lane >> 4;
  int sl = lane & 15;
  if (node >= n) return;

  uint4 fdu = *(const uint4*)(fd + (size_t)node * 128 + sl * 8);
  float fdv[8];
  fdv[0] = bflo(fdu.x); fdv[1] = bfhi(fdu.x);
  fdv[2] = bflo(fdu.y); fdv[3] = bfhi(fdu.y);
  fdv[4] = bflo(fdu.z); fdv[5] = bfhi(fdu.z);
  fdv[6] = bflo(fdu.w); fdv[7] = bfhi(fdu.w);
  float4 at0 = *(const float4*)(attn + sl * 8);
  float4 at1 = *(const float4*)(attn + sl * 8 + 4);
  float atv[8] = {at0.x, at0.y, at0.z, at0.w, at1.x, at1.y, at1.z, at1.w};

  int s0 = offs[node], s1 = offs[node + 1];
  float acc[8] = {0.f, 0.f, 0.f, 0.f, 0.f, 0.f, 0.f, 0.f};
  float sacc = 0.f;

  int i = s0 + slot;
  int src = (i < s1) ? esrc_all[i] : 0;
  while (i < s1) {
    int ni = i + 4;
    int nsrc = (ni < s1) ? esrc_all[ni] : 0;
    uint4 fu = *(const uint4*)(fs + (size_t)src * 128 + sl * 8);
    float fv[8];
    fv[0] = bflo(fu.x); fv[1] = bfhi(fu.x);
    fv[2] = bflo(fu.y); fv[3] = bfhi(fu.y);
    fv[4] = bflo(fu.z); fv[5] = bfhi(fu.z);
    fv[6] = bflo(fu.w); fv[7] = bfhi(fu.w);
    float p = 0.f;
#pragma unroll
    for (int j = 0; j < 8; j++) {
      float tt = fv[j] + fdv[j];
      tt = (tt > 0.f) ? tt : 0.2f * tt;
      p += tt * atv[j];
    }
    p += __shfl_xor(p, 1);
    p += __shfl_xor(p, 2);
    float ex = __expf(p);
    sacc += ex;
#pragma unroll
    for (int j = 0; j < 8; j++) acc[j] += ex * fv[j];
    i = ni;
    src = nsrc;
  }

#pragma unroll
  for (int j = 0; j < 8; j++) {
    acc[j] += __shfl_xor(acc[j], 16);
    acc[j] += __shfl_xor(acc[j], 32);
  }
  sacc += __shfl_xor(sacc, 16);
  sacc += __shfl_xor(sacc, 32);

  if (slot == 0) {
    float inv = (s1 > s0) ? (1.f / sacc) : 0.f;
    uint4 o;
    o.x = (unsigned)f2bf(fmaxf(acc[0] * inv, 0.f)) | ((unsigned)f2bf(fmaxf(acc[1] * inv, 0.f)) << 16);
    o.y = (unsigned)f2bf(fmaxf(acc[2] * inv, 0.f)) | ((unsigned)f2bf(fmaxf(acc[3] * inv, 0.f)) << 16);
    o.z = (unsigned)f2bf(fmaxf(acc[4] * inv, 0.f)) | ((unsigned)f2bf(fmaxf(acc[5] * inv, 0.f)) << 16);
    o.w = (unsigned)f2bf(fmaxf(acc[6] * inv, 0.f)) | ((unsigned)f2bf(fmaxf(acc[7] * inv, 0.f)) << 16);
    *(uint4*)(zout + (size_t)node * 128 + sl * 8) = o;
  }
}

// ---------------- semantic attention, MFMA-fused ----------------
__global__ __launch_bounds__(256) void satt_mfma_k(
    const us* __restrict__ z0, const us* __restrict__ z1,
    const us* __restrict__ Wat, const float* __restrict__ ba,
    const float* __restrict__ Wo, float* __restrict__ w_acc, int M)
{
  __shared__ us As[128 * 40];
  __shared__ us Bs[128 * 40];
  const us* Z = blockIdx.z ? z1 : z0;
  const int t = threadIdx.x;
  const int rowBase = blockIdx.y * 128;
  const int srow = t >> 1, sk = (t & 1) * 16;
  const int w = t >> 6, lane = t & 63;
  const int wm = w >> 1, wn = w & 1;
  const int m16 = lane & 15, q = lane >> 4;

  f32x4 acc[4][4];
  const f32x4 zero = {0.f, 0.f, 0.f, 0.f};
#pragma unroll
  for (int i = 0; i < 4; i++)
#pragma unroll
    for (int j = 0; j < 4; j++) acc[i][j] = zero;

  int arow = rowBase + srow;
  if (arow >= M) arow = M - 1;
  const us* aptr = Z + (size_t)arow * 128;
  const us* bptr = Wat + (size_t)srow * 128;

  for (int k0 = 0; k0 < 128; k0 += 32) {
    uint4 a0 = ((const uint4*)(aptr + k0 + sk))[0];
    uint4 a1 = ((const uint4*)(aptr + k0 + sk))[1];
    uint4 b0 = ((const uint4*)(bptr + k0 + sk))[0];
    uint4 b1 = ((const uint4*)(bptr + k0 + sk))[1];
    ((uint4*)&As[srow * 40 + sk])[0] = a0;
    ((uint4*)&As[srow * 40 + sk])[1] = a1;
    ((uint4*)&Bs[srow * 40 + sk])[0] = b0;
    ((uint4*)&Bs[srow * 40 + sk])[1] = b1;
    __syncthreads();
    s16x8 af[4], bfr[4];
#pragma unroll
    for (int mi = 0; mi < 4; mi++)
      af[mi] = *(const s16x8*)&As[(wm * 64 + mi * 16 + m16) * 40 + q * 8];
#pragma unroll
    for (int ni = 0; ni < 4; ni++)
      bfr[ni] = *(const s16x8*)&Bs[(wn * 64 + ni * 16 + m16) * 40 + q * 8];
#pragma unroll
    for (int mi = 0; mi < 4; mi++)
#pragma unroll
      for (int ni = 0; ni < 4; ni++)
        acc[mi][ni] = __builtin_amdgcn_mfma_f32_16x16x32_bf16(af[mi], bfr[ni], acc[mi][ni], 0, 0, 0);
    __syncthreads();
  }

  float s = 0.f;
#pragma unroll
  for (int ni = 0; ni < 4; ni++) {
    int col = wn * 64 + ni * 16 + m16;
    float bcol = ba[col], wcol = Wo[col];
#pragma unroll
    for (int mi = 0; mi < 4; mi++) {
#pragma unroll
      for (int r = 0; r < 4; r++) {
        int row = rowBase + wm * 64 + mi * 16 + q * 4 + r;
        if (row < M) s += tanhf(acc[mi][ni][r] + bcol) * wcol;
      }
    }
  }
  for (int d = 1; d < 64; d <<= 1) s += __shfl_xor(s, d);
  __shared__ float red[4];
  if (lane == 0) red[w] = s;
  __syncthreads();
  if (t == 0) atomicAdd(&w_acc[blockIdx.z], red[0] + red[1] + red[2] + red[3]);
}

__global__ void beta_k(const float* __restrict__ w_acc, float* __restrict__ beta, float invn) {
  if (threadIdx.x == 0 && blockIdx.x == 0) {
    float w0 = w_acc[0] * invn, w1 = w_acc[1] * invn;
    float m = fmaxf(w0, w1);
    float e0 = expf(w0 - m), e1 = expf(w1 - m);
    float s = e0 + e1;
    beta[0] = e0 / s; beta[1] = e1 / s;
    float w2 = w_acc[2] * invn, w3 = w_acc[3] * invn;
    float m2 = fmaxf(w2, w3);
    float e2 = expf(w2 - m2), e3 = expf(w3 - m2);
    float s2 = e2 + e3;
    beta[2] = e2 / s2; beta[3] = e3 / s2;
  }
}

static __device__ __forceinline__ unsigned int comb2(unsigned int a, unsigned int b, float b0, float b1) {
  float lo = bflo(a) * b0 + bflo(b) * b1;
  float hi = bfhi(a) * b0 + bfhi(b) * b1;
  return (unsigned int)f2bf(lo) | ((unsigned int)f2bf(hi) << 16);
}

__global__ __launch_bounds__(256) void combine2_k(const us* __restrict__ zb_all,
                                                  const float* __restrict__ beta,
                                                  us* __restrict__ haob, us* __restrict__ htob, int n8) {
  int z = blockIdx.z;
  const us* za = zb_all + (size_t)(2 * z) * N_NODES * 128;
  const us* zbv = zb_all + (size_t)(2 * z + 1) * N_NODES * 128;
  float b0 = beta[2 * z], b1 = beta[2 * z + 1];
  us* outv = z ? htob : haob;
  for (int i = blockIdx.x * 256 + threadIdx.x; i < n8; i += gridDim.x * 256) {
    uint4 a = ((const uint4*)za)[i];
    uint4 b = ((const uint4*)zbv)[i];
    uint4 o;
    o.x = comb2(a.x, b.x, b0, b1);
    o.y = comb2(a.y, b.y, b0, b1);
    o.z = comb2(a.z, b.z, b0, b1);
    o.w = comb2(a.w, b.w, b0, b1);
    ((uint4*)outv)[i] = o;
  }
}

// -------- predictor fully fused --------
__global__ __launch_bounds__(256) void pred_fused_k(
    const us* __restrict__ haob, const us* __restrict__ htob,
    const int* __restrict__ pos_e, const int* __restrict__ neg_e,
    const us* __restrict__ prW1t, const float* __restrict__ prb1,
    const float* __restrict__ prW2, const float* __restrict__ prb2,
    float* __restrict__ out, int M)
{
  __shared__ us As[128 * 40];
  __shared__ us Bs[128 * 40];
  const int z = blockIdx.z;
  const int* pe = z ? neg_e : pos_e;
  float* o = out + (size_t)z * M;

  const int t = threadIdx.x;
  const int rowBase = blockIdx.x * 128;
  const int srow = t >> 1, sk = (t & 1) * 16;
  const int w = t >> 6, lane = t & 63;
  const int wm = w >> 1, wn = w & 1;
  const int m16 = lane & 15, q = lane >> 4;

  f32x4 acc[4][4];
  const f32x4 zero = {0.f, 0.f, 0.f, 0.f};
#pragma unroll
  for (int i = 0; i < 4; i++)
#pragma unroll
    for (int j = 0; j < 4; j++) acc[i][j] = zero;

  int arow = rowBase + srow;
  if (arow >= M) arow = M - 1;
  const int srcn = pe[arow];
  const int dstn = pe[M + arow];
  const us* bptr = prW1t + (size_t)srow * 256;

  for (int k0 = 0; k0 < 256; k0 += 32) {
    const us* asrc = (k0 < 128) ? (haob + (size_t)srcn * 128 + k0 + sk)
                                : (htob + (size_t)dstn * 128 + (k0 - 128) + sk);
    uint4 a0 = ((const uint4*)asrc)[0];
    uint4 a1 = ((const uint4*)asrc)[1];
    uint4 b0 = ((const uint4*)(bptr + k0 + sk))[0];
    uint4 b1 = ((const uint4*)(bptr + k0 + sk))[1];
    ((uint4*)&As[srow * 40 + sk])[0] = a0;
    ((uint4*)&As[srow * 40 + sk])[1] = a1;
    ((uint4*)&Bs[srow * 40 + sk])[0] = b0;
    ((uint4*)&Bs[srow * 40 + sk])[1] = b1;
    __syncthreads();
    s16x8 af[4], bfr[4];
#pragma unroll
    for (int mi = 0; mi < 4; mi++)
      af[mi] = *(const s16x8*)&As[(wm * 64 + mi * 16 + m16) * 40 + q * 8];
#pragma unroll
    for (int ni = 0; ni < 4; ni++)
      bfr[ni] = *(const s16x8*)&Bs[(wn * 64 + ni * 16 + m16) * 40 + q * 8];
#pragma unroll
    for (int mi = 0; mi < 4; mi++)
#pragma unroll
      for (int ni = 0; ni < 4; ni++)
        acc[mi][ni] = __builtin_amdgcn_mfma_f32_16x16x32_bf16(af[mi], bfr[ni], acc[mi][ni], 0, 0, 0);
    __syncthreads();
  }

  float* rsum = (float*)As;
  if (t < 128) rsum[t] = 0.f;
  __syncthreads();
  float bcol[4], w2c[4];
#pragma unroll
  for (int ni = 0; ni < 4; ni++) {
    int col = wn * 64 + ni * 16 + m16;
    bcol[ni] = prb1[col];
    w2c[ni] = prW2[col];
  }
#pragma unroll
  for (int mi = 0; mi < 4; mi++) {
#pragma unroll
    for (int r = 0; r < 4; r++) {
      float s = 0.f;
#pragma unroll
      for (int ni = 0; ni < 4; ni++)
        s += fmaxf(acc[mi][ni][r] + bcol[ni], 0.f) * w2c[ni];
      s += __shfl_xor(s, 1);
      s += __shfl_xor(s, 2);
      s += __shfl_xor(s, 4);
      s += __shfl_xor(s, 8);
      if (m16 == 0) atomicAdd(&rsum[wm * 64 + mi * 16 + q * 4 + r], s);
    }
  }
  __syncthreads();
  if (t < 128) {
    int row = rowBase + t;
    if (row < M) o[row] = 1.f / (1.f + expf(-(rsum[t] + prb2[0])));
  }
}

extern "C" void kernel_launch(void* const* d_in, const int* in_sizes, int n_in,
                              void* d_out, int out_size, void* d_ws, size_t ws_size,
                              hipStream_t stream) {
  const float* PE   = (const float*)d_in[0];
  const float* GE   = (const float*)d_in[1];
  const float* W1   = (const float*)d_in[2];
  const float* b1   = (const float*)d_in[3];
  const float* W2   = (const float*)d_in[4];
  const float* b2   = (const float*)d_in[5];
  const float* gWs  = (const float*)d_in[6];
  const float* gbs  = (const float*)d_in[7];
  const float* gWd  = (const float*)d_in[8];
  const float* gbd  = (const float*)d_in[9];
  const float* gattn= (const float*)d_in[10];
  const float* pW1  = (const float*)d_in[11];
  const float* pb1  = (const float*)d_in[12];
  const float* pW2  = (const float*)d_in[13];
  const float* gaW1 = (const float*)d_in[14];
  const float* gab1 = (const float*)d_in[15];
  const float* gaW2 = (const float*)d_in[16];
  const float* prW1 = (const float*)d_in[17];
  const float* prb1 = (const float*)d_in[18];
  const float* prW2 = (const float*)d_in[19];
  const float* prb2 = (const float*)d_in[20];
  const int* e_aa = (const int*)d_in[21];
  const int* e_ta = (const int*)d_in[22];
  const int* e_tt = (const int*)d_in[23];
  const int* e_at = (const int*)d_in[24];
  const int* pos_e = (const int*)d_in[25];
  const int* neg_e = (const int*)d_in[26];
  float* out = (float*)d_out;

  // ---- workspace layout ----
  us* usws = (us*)d_ws;
  size_t o = 0;
  us* ha_b   = usws + o; o += (size_t)N_NODES * 256;
  us* ht_b   = usws + o; o += (size_t)N_NODES * 256;
  us* fs_all = usws + o; o += (size_t)8 * N_NODES * 128;
  us* zb_all = usws + o; o += (size_t)4 * N_NODES * 128;
  us* haob   = usws + o; o += (size_t)N_NODES * 128;
  us* htob   = usws + o; o += (size_t)N_NODES * 128;
  us* W2t    = usws + o; o += 262144;
  us* W1t    = usws + o; o += 131072;
  us* gWst   = usws + o; o += 131072;
  us* gWdt   = usws + o; o += 131072;
  us* prW1t  = usws + o; o += 32768;
  us* WaPt   = usws + o; o += 16384;
  us* WaGt   = usws + o; o += 16384;
  float* w_acc = (float*)(usws + o); o += 16;
  float* beta  = w_acc + 4;
  int* ib = (int*)(usws + o);
  size_t io = 0;
  int* bhist = ib + io; io += 1024;       // 784 used
  int* bbase = ib + io; io += 1024;       // 785 used
  int* bcur  = ib + io; io += 1024;
  int* offs4 = ib + io; io += NG4 + 4;
  int* esrc  = ib + io; io += ETOT;
  // packed (dst<<16|src) staging aliases zb_all (dead until aggregate4_k writes it)
  unsigned int* epack = (unsigned int*)zb_all;

  dim3 blk256(256), blk1024(1024);
  const int MT = idiv(N_NODES, 128);   // 391
  const int ET = idiv(EP_EDGES, 128);  // 1563

  // 1) weights
  wtrans_all_k<<<dim3(64, 1, 7), blk256, 0, stream>>>(
      W2, W1, gWs, gWd, prW1, pW1, gaW1, W2t, W1t, gWst, gWdt, prW1t, WaPt, WaGt);

  // 2-3) input projections
  proj_gemm_k<<<dim3(MT), blk256, 0, stream>>>(PE, W2t, b2, ha_b, N_NODES, 1024);
  proj_gemm_k<<<dim3(MT), blk256, 0, stream>>>(GE, W1t, b1, ht_b, N_NODES, 512);

  // 4) all 8 GAT feature GEMMs
  gat_gemm8_k<<<dim3(1, MT, 8), blk256, 0, stream>>>(ha_b, ht_b, gWst, gWdt, gbs, gbd, fs_all, N_NODES);

  // 5-8) CSR build v2 (bucketed two-phase, dense writes)
  hipMemsetAsync(bhist, 0, 4 * NBUCK * sizeof(int), stream);
  bhist_k<<<dim3(idiv(E_EDGES, 2048), 1, 4), blk256, 0, stream>>>(e_aa, e_ta, e_tt, e_at, bhist);
  bscan_k<<<1, blk1024, 0, stream>>>(bhist, bbase, bcur);
  binscatter_k<<<dim3(idiv(E_EDGES, 4096), 1, 4), blk256, 0, stream>>>(e_aa, e_ta, e_tt, e_at, bcur, epack);
  bucketscatter2_k<<<dim3(NBUCK, 1, 4), blk256, 0, stream>>>(bbase, epack, esrc, offs4);

  // 9) all 4 edge-softmax aggregations
  aggregate4_k<<<dim3(idiv(N_NODES, 4), 1, 4), blk256, 0, stream>>>(fs_all, gattn, offs4, esrc, zb_all, N_NODES);

  // 10-11) semantic attention
  hipMemsetAsync(w_acc, 0, 4 * sizeof(float), stream);
  satt_mfma_k<<<dim3(1, MT, 2), blk256, 0, stream>>>(
      zb_all, zb_all + (size_t)N_NODES * 128, WaPt, pb1, pW2, w_acc + 0, N_NODES);
  satt_mfma_k<<<dim3(1, MT, 2), blk256, 0, stream>>>(
      zb_all + (size_t)2 * N_NODES * 128, zb_all + (size_t)3 * N_NODES * 128, WaGt, gab1, gaW2, w_acc + 2, N_NODES);
  beta_k<<<1, 64, 0, stream>>>(w_acc, beta, 1.0f / (float)N_NODES);

  // 12) combine both groups
  combine2_k<<<dim3(2048, 1, 2), blk256, 0, stream>>>(zb_all, beta, haob, htob, N_NODES * 128 / 8);

  // 13) fully fused predictor (pos+neg)
  pred_fused_k<<<dim3(ET, 1, 2), blk256, 0, stream>>>(
      haob, htob, pos_e, neg_e, prW1t, prb1, prW2, prb2, out, EP_EDGES);
}

// Round 3
// 976.222 us; speedup vs baseline: 1.5975x; 1.0930x over previous
//
#include <hip/hip_runtime.h>
#include <math.h>

#define N_NODES 50000
#define E_EDGES 800000
#define EP_EDGES 200000
#define NG4 (4 * N_NODES)
#define ETOT (4 * E_EDGES)
#define NBUCK 196   // ceil(50000/256)

static inline int idiv(int a, int b) { return (a + b - 1) / b; }

typedef short s16x8 __attribute__((ext_vector_type(8)));
typedef float f32x4 __attribute__((ext_vector_type(4)));
typedef unsigned short us;

static __device__ __forceinline__ us f2bf(float f) {
  unsigned int u = __float_as_uint(f);
  u += 0x7FFFu + ((u >> 16) & 1u);
  return (us)(u >> 16);
}
static __device__ __forceinline__ float bflo(unsigned int u) { return __uint_as_float(u << 16); }
static __device__ __forceinline__ float bfhi(unsigned int u) { return __uint_as_float(u & 0xffff0000u); }

// ---------------- fused weight transpose+convert: 7 segments via blockIdx.z ----------------
__global__ __launch_bounds__(256) void wtrans_all_k(
    const float* __restrict__ W2, const float* __restrict__ W1,
    const float* __restrict__ gWs, const float* __restrict__ gWd,
    const float* __restrict__ prW1, const float* __restrict__ pW1,
    const float* __restrict__ gaW1,
    us* __restrict__ W2t, us* __restrict__ W1t, us* __restrict__ gWst,
    us* __restrict__ gWdt, us* __restrict__ prW1t, us* __restrict__ WaPt,
    us* __restrict__ WaGt)
{
  const float* src; us* dst; int ks, nsh, total;
  switch (blockIdx.z) {
    case 0: src = W2;   dst = W2t;   ks = 10; nsh = 8; total = 262144; break;
    case 1: src = W1;   dst = W1t;   ks = 9;  nsh = 8; total = 131072; break;
    case 2: src = gWs;  dst = gWst;  ks = 8;  nsh = 7; total = 131072; break;
    case 3: src = gWd;  dst = gWdt;  ks = 8;  nsh = 7; total = 131072; break;
    case 4: src = prW1; dst = prW1t; ks = 8;  nsh = 7; total = 32768;  break;
    case 5: src = pW1;  dst = WaPt;  ks = 7;  nsh = 7; total = 16384;  break;
    default: src = gaW1; dst = WaGt; ks = 7;  nsh = 7; total = 16384;  break;
  }
  int psh = ks + nsh;
  int Km1 = (1 << ks) - 1;
  int pm1 = (1 << psh) - 1;
  for (int gid = blockIdx.x * 256 + threadIdx.x; gid < total; gid += gridDim.x * 256) {
    int mat = gid >> psh;
    int rem = gid & pm1;
    int n = rem >> ks, k = rem & Km1;
    dst[gid] = f2bf(src[((size_t)mat << psh) + ((size_t)k << nsh) + n]);
  }
}

// ------- both input projections in ONE dispatch (z=0: PE K=1024 -> ha; z=1: GE K=512 -> ht) -------
// 64-row tiles (grid 782x2 = 1564 blocks, ~6/CU) to fix the occupancy/latency bound seen at 128-row.
// 4 waves as 1x4: wave w covers cols w*64..w*64+63, all 64 rows; acc 4x4 frags.
__global__ __launch_bounds__(256) void proj2_gemm_k(
    const float* __restrict__ PE, const float* __restrict__ GE,
    const us* __restrict__ W2t, const us* __restrict__ W1t,
    const float* __restrict__ b2, const float* __restrict__ b1,
    us* __restrict__ ha_b, us* __restrict__ ht_b, int M)
{
  const int z = blockIdx.z;
  const float* A = z ? GE : PE;
  const us* Bt = z ? W1t : W2t;
  const float* bias = z ? b1 : b2;
  us* C = z ? ht_b : ha_b;
  const int K = z ? 512 : 1024;

  __shared__ us As[64 * 40];
  __shared__ us Bs[256 * 40];
  const int t = threadIdx.x;
  const int rowBase = blockIdx.x * 64;
  const int srow = t >> 2, skf = (t & 3) * 8;   // each thread: 8 consecutive floats of A
  const int w = t >> 6, lane = t & 63;
  const int m16 = lane & 15, q = lane >> 4;

  f32x4 acc[4][4];
  const f32x4 zero = {0.f, 0.f, 0.f, 0.f};
#pragma unroll
  for (int i = 0; i < 4; i++)
#pragma unroll
    for (int j = 0; j < 4; j++) acc[i][j] = zero;

  int arow = rowBase + srow;
  if (arow >= M) arow = M - 1;
  const float* aptr = A + (size_t)arow * K;
  const us* bptr = Bt + (size_t)t * K;

  for (int k0 = 0; k0 < K; k0 += 32) {
    const float* ap = aptr + k0 + skf;
    float4 x0 = ((const float4*)ap)[0];
    float4 x1 = ((const float4*)ap)[1];
    uint4 p;
    p.x = (unsigned)f2bf(x0.x) | ((unsigned)f2bf(x0.y) << 16);
    p.y = (unsigned)f2bf(x0.z) | ((unsigned)f2bf(x0.w) << 16);
    p.z = (unsigned)f2bf(x1.x) | ((unsigned)f2bf(x1.y) << 16);
    p.w = (unsigned)f2bf(x1.z) | ((unsigned)f2bf(x1.w) << 16);
    uint4 b0 = ((const uint4*)(bptr + k0))[0];
    uint4 b1v = ((const uint4*)(bptr + k0))[1];
    uint4 b2v = ((const uint4*)(bptr + k0))[2];
    uint4 b3v = ((const uint4*)(bptr + k0))[3];
    ((uint4*)&As[srow * 40 + skf])[0] = p;
    ((uint4*)&Bs[t * 40])[0] = b0;
    ((uint4*)&Bs[t * 40])[1] = b1v;
    ((uint4*)&Bs[t * 40])[2] = b2v;
    ((uint4*)&Bs[t * 40])[3] = b3v;
    __syncthreads();
    s16x8 af[4], bfr[4];
#pragma unroll
    for (int mi = 0; mi < 4; mi++)
      af[mi] = *(const s16x8*)&As[(mi * 16 + m16) * 40 + q * 8];
#pragma unroll
    for (int ni = 0; ni < 4; ni++)
      bfr[ni] = *(const s16x8*)&Bs[(w * 64 + ni * 16 + m16) * 40 + q * 8];
#pragma unroll
    for (int mi = 0; mi < 4; mi++)
#pragma unroll
      for (int ni = 0; ni < 4; ni++)
        acc[mi][ni] = __builtin_amdgcn_mfma_f32_16x16x32_bf16(af[mi], bfr[ni], acc[mi][ni], 0, 0, 0);
    __syncthreads();
  }

#pragma unroll
  for (int ni = 0; ni < 4; ni++) {
    int col = w * 64 + ni * 16 + m16;
    float bcol = bias[col];
#pragma unroll
    for (int mi = 0; mi < 4; mi++) {
#pragma unroll
      for (int r = 0; r < 4; r++) {
        int row = rowBase + mi * 16 + q * 4 + r;
        if (row < M) C[(size_t)row * 256 + col] = f2bf(acc[mi][ni][r] + bcol);
      }
    }
  }
}

// ------- 8 GAT feature GEMMs in one dispatch -------
__global__ __launch_bounds__(256) void gat_gemm8_k(
    const us* __restrict__ ha, const us* __restrict__ ht,
    const us* __restrict__ gWst, const us* __restrict__ gWdt,
    const float* __restrict__ gbs, const float* __restrict__ gbd,
    us* __restrict__ fs_all, int M)
{
  __shared__ us As[128 * 40];
  __shared__ us Bs[128 * 40];
  const int z = blockIdx.z, g = z >> 1, j = z & 1;
  const us* A = (((j ? 0xC : 0x6) >> g) & 1) ? ht : ha;
  const us* Bt = (j ? gWdt : gWst) + ((size_t)g << 15);
  const float* bias = (j ? gbd : gbs) + g * 128;
  us* C = fs_all + (size_t)z * M * 128;

  const int t = threadIdx.x;
  const int rowBase = blockIdx.y * 128;
  const int srow = t >> 1, sk = (t & 1) * 16;
  const int w = t >> 6, lane = t & 63;
  const int wm = w >> 1, wn = w & 1;
  const int m16 = lane & 15, q = lane >> 4;

  f32x4 acc[4][4];
  const f32x4 zero = {0.f, 0.f, 0.f, 0.f};
#pragma unroll
  for (int i = 0; i < 4; i++)
#pragma unroll
    for (int jj = 0; jj < 4; jj++) acc[i][jj] = zero;

  int arow = rowBase + srow;
  if (arow >= M) arow = M - 1;
  const us* aptr = A + (size_t)arow * 256;
  const us* bptr = Bt + (size_t)srow * 256;

  for (int k0 = 0; k0 < 256; k0 += 32) {
    uint4 a0 = ((const uint4*)(aptr + k0 + sk))[0];
    uint4 a1 = ((const uint4*)(aptr + k0 + sk))[1];
    uint4 b0 = ((const uint4*)(bptr + k0 + sk))[0];
    uint4 b1 = ((const uint4*)(bptr + k0 + sk))[1];
    ((uint4*)&As[srow * 40 + sk])[0] = a0;
    ((uint4*)&As[srow * 40 + sk])[1] = a1;
    ((uint4*)&Bs[srow * 40 + sk])[0] = b0;
    ((uint4*)&Bs[srow * 40 + sk])[1] = b1;
    __syncthreads();
    s16x8 af[4], bfr[4];
#pragma unroll
    for (int mi = 0; mi < 4; mi++)
      af[mi] = *(const s16x8*)&As[(wm * 64 + mi * 16 + m16) * 40 + q * 8];
#pragma unroll
    for (int ni = 0; ni < 4; ni++)
      bfr[ni] = *(const s16x8*)&Bs[(wn * 64 + ni * 16 + m16) * 40 + q * 8];
#pragma unroll
    for (int mi = 0; mi < 4; mi++)
#pragma unroll
      for (int ni = 0; ni < 4; ni++)
        acc[mi][ni] = __builtin_amdgcn_mfma_f32_16x16x32_bf16(af[mi], bfr[ni], acc[mi][ni], 0, 0, 0);
    __syncthreads();
  }

#pragma unroll
  for (int ni = 0; ni < 4; ni++) {
    int col = wn * 64 + ni * 16 + m16;
    float bcol = bias[col];
#pragma unroll
    for (int mi = 0; mi < 4; mi++) {
#pragma unroll
      for (int r = 0; r < 4; r++) {
        int row = rowBase + wm * 64 + mi * 16 + q * 4 + r;
        if (row < M) C[(size_t)row * 128 + col] = f2bf(acc[mi][ni][r] + bcol);
      }
    }
  }
}

// ---------------- CSR build v2: coarse-bucket two-phase ----------------
__global__ __launch_bounds__(256) void bhist_k(
    const int* __restrict__ e_aa, const int* __restrict__ e_ta,
    const int* __restrict__ e_tt, const int* __restrict__ e_at,
    int* __restrict__ bhist)
{
  int g = blockIdx.z;
  const int* e = g == 0 ? e_aa : g == 1 ? e_ta : g == 2 ? e_tt : e_at;
  const int* dstp = e + E_EDGES;
  __shared__ int lh[256];
  int t = threadIdx.x;
  lh[t] = 0;
  __syncthreads();
  int base = blockIdx.x * 2048;
#pragma unroll
  for (int r = 0; r < 8; r++) {
    int i = base + r * 256 + t;
    if (i < E_EDGES) atomicAdd(&lh[dstp[i] >> 8], 1);
  }
  __syncthreads();
  if (t < NBUCK && lh[t]) atomicAdd(&bhist[g * NBUCK + t], lh[t]);
}

__global__ __launch_bounds__(1024) void bscan_k(const int* __restrict__ bhist,
                                                int* __restrict__ bbase, int* __restrict__ bcur) {
  __shared__ int tmp[1024];
  int t = threadIdx.x;
  int v = (t < 4 * NBUCK) ? bhist[t] : 0;
  tmp[t] = v;
  __syncthreads();
  int x = v;
  for (int d = 1; d < 1024; d <<= 1) {
    int y = (t >= d) ? tmp[t - d] : 0;
    __syncthreads();
    x += y;
    tmp[t] = x;
    __syncthreads();
  }
  if (t < 4 * NBUCK) {
    int e = x - v;
    bbase[t] = e;
    bcur[t] = e;
  }
  if (t == 4 * NBUCK - 1) bbase[4 * NBUCK] = x;
}

__global__ __launch_bounds__(256) void binscatter_k(
    const int* __restrict__ e_aa, const int* __restrict__ e_ta,
    const int* __restrict__ e_tt, const int* __restrict__ e_at,
    int* __restrict__ bcur, unsigned int* __restrict__ epack)
{
  int g = blockIdx.z;
  const int* e = g == 0 ? e_aa : g == 1 ? e_ta : g == 2 ? e_tt : e_at;
  const int* srcp = e;
  const int* dstp = e + E_EDGES;
  const int base = blockIdx.x * 4096;
  const int cnt = min(4096, E_EDGES - base);
  __shared__ int lh[256], sc[256], lcur[256], gb[256];
  __shared__ unsigned int spack[4096];
  __shared__ unsigned short sbuck[4096];
  const int t = threadIdx.x;
  lh[t] = 0;
  __syncthreads();
  int ds[16], ss[16];
#pragma unroll
  for (int r = 0; r < 16; r++) {
    int i = r * 256 + t;
    if (i < cnt) {
      ds[r] = dstp[base + i];
      ss[r] = srcp[base + i];
      atomicAdd(&lh[ds[r] >> 8], 1);
    } else ds[r] = -1;
  }
  __syncthreads();
  int v = lh[t];
  sc[t] = v;
  __syncthreads();
  int x = v;
  for (int d = 1; d < 256; d <<= 1) {
    int y = (t >= d) ? sc[t - d] : 0;
    __syncthreads();
    x += y;
    sc[t] = x;
    __syncthreads();
  }
  lcur[t] = x - v;
  if (t < NBUCK) gb[t] = atomicAdd(&bcur[g * NBUCK + t], v);
  __syncthreads();
#pragma unroll
  for (int r = 0; r < 16; r++) {
    if (ds[r] >= 0) {
      int b = ds[r] >> 8;
      int rank = atomicAdd(&lcur[b], 1);
      spack[rank] = ((unsigned int)ds[r] << 16) | (unsigned int)ss[r];
      sbuck[rank] = (unsigned short)b;
    }
  }
  __syncthreads();
  for (int j = t; j < cnt; j += 256) {
    int b = sbuck[j];
    epack[gb[b] + (j - (sc[b] - lh[b]))] = spack[j];
  }
}

__global__ __launch_bounds__(256) void bucketscatter2_k(
    const int* __restrict__ bbase, const unsigned int* __restrict__ epack,
    int* __restrict__ esrc_all, int* __restrict__ offs4)
{
  int g = blockIdx.z, b = blockIdx.x;
  int gb = g * NBUCK + b;
  int start = bbase[gb], end = bbase[gb + 1];
  int ndst = min(256, N_NODES - (b << 8));
  __shared__ int lh[256], cur[256];
  int t = threadIdx.x;
  lh[t] = 0;
  __syncthreads();
  for (int i = start + t; i < end; i += 256)
    atomicAdd(&lh[(epack[i] >> 16) & 255], 1);
  __syncthreads();
  int v = lh[t];
  cur[t] = v;
  __syncthreads();
  int x = v;
  for (int d = 1; d < 256; d <<= 1) {
    int y = (t >= d) ? cur[t - d] : 0;
    __syncthreads();
    x += y;
    cur[t] = x;
    __syncthreads();
  }
  int mybase = start + x - v;
  if (t < ndst) offs4[g * N_NODES + (b << 8) + t] = mybase;
  cur[t] = mybase;
  __syncthreads();
  if (gb == 4 * NBUCK - 1 && t == 0) offs4[NG4] = end;
  unsigned int pk = (start + t < end) ? epack[start + t] : 0u;
  for (int i = start + t; i < end; i += 256) {
    unsigned int nk = (i + 256 < end) ? epack[i + 256] : 0u;
    int dl = (pk >> 16) & 255;
    int pos = atomicAdd(&cur[dl], 1);
    esrc_all[pos] = (int)(pk & 0xffffu);
    pk = nk;
  }
}

// -------- GATv2 edge-softmax + aggregate, all 4 graphs (z=graph) --------
__global__ __launch_bounds__(256) void aggregate4_k(
    const us* __restrict__ fs_all, const float* __restrict__ gattn,
    const int* __restrict__ offs4, const int* __restrict__ esrc_all,
    us* __restrict__ zb_all, int n)
{
  int g = blockIdx.z;
  const us* fs = fs_all + (size_t)(2 * g) * n * 128;
  const us* fd = fs_all + (size_t)(2 * g + 1) * n * 128;
  const float* attn = gattn + g * 128;
  us* zout = zb_all + (size_t)g * n * 128;
  const int* offs = offs4 + (size_t)g * n;

  int node = blockIdx.x * 4 + (threadIdx.x >> 6);
  int lane = threadIdx.x & 63;
  int slot = lane >> 4;
  int sl = lane & 15;
  if (node >= n) return;

  uint4 fdu = *(const uint4*)(fd + (size_t)node * 128 + sl * 8);
  float fdv[8];
  fdv[0] = bflo(fdu.x); fdv[1] = bfhi(fdu.x);
  fdv[2] = bflo(fdu.y); fdv[3] = bfhi(fdu.y);
  fdv[4] = bflo(fdu.z); fdv[5] = bfhi(fdu.z);
  fdv[6] = bflo(fdu.w); fdv[7] = bfhi(fdu.w);
  float4 at0 = *(const float4*)(attn + sl * 8);
  float4 at1 = *(const float4*)(attn + sl * 8 + 4);
  float atv[8] = {at0.x, at0.y, at0.z, at0.w, at1.x, at1.y, at1.z, at1.w};

  int s0 = offs[node], s1 = offs[node + 1];
  float acc[8] = {0.f, 0.f, 0.f, 0.f, 0.f, 0.f, 0.f, 0.f};
  float sacc = 0.f;

  int i = s0 + slot;
  int src = (i < s1) ? esrc_all[i] : 0;
  while (i < s1) {
    int ni = i + 4;
    int nsrc = (ni < s1) ? esrc_all[ni] : 0;
    uint4 fu = *(const uint4*)(fs + (size_t)src * 128 + sl * 8);
    float fv[8];
    fv[0] = bflo(fu.x); fv[1] = bfhi(fu.x);
    fv[2] = bflo(fu.y); fv[3] = bfhi(fu.y);
    fv[4] = bflo(fu.z); fv[5] = bfhi(fu.z);
    fv[6] = bflo(fu.w); fv[7] = bfhi(fu.w);
    float p = 0.f;
#pragma unroll
    for (int j = 0; j < 8; j++) {
      float tt = fv[j] + fdv[j];
      tt = (tt > 0.f) ? tt : 0.2f * tt;
      p += tt * atv[j];
    }
    p += __shfl_xor(p, 1);
    p += __shfl_xor(p, 2);
    float ex = __expf(p);
    sacc += ex;
#pragma unroll
    for (int j = 0; j < 8; j++) acc[j] += ex * fv[j];
    i = ni;
    src = nsrc;
  }

#pragma unroll
  for (int j = 0; j < 8; j++) {
    acc[j] += __shfl_xor(acc[j], 16);
    acc[j] += __shfl_xor(acc[j], 32);
  }
  sacc += __shfl_xor(sacc, 16);
  sacc += __shfl_xor(sacc, 32);

  if (slot == 0) {
    float inv = (s1 > s0) ? (1.f / sacc) : 0.f;
    uint4 o;
    o.x = (unsigned)f2bf(fmaxf(acc[0] * inv, 0.f)) | ((unsigned)f2bf(fmaxf(acc[1] * inv, 0.f)) << 16);
    o.y = (unsigned)f2bf(fmaxf(acc[2] * inv, 0.f)) | ((unsigned)f2bf(fmaxf(acc[3] * inv, 0.f)) << 16);
    o.z = (unsigned)f2bf(fmaxf(acc[4] * inv, 0.f)) | ((unsigned)f2bf(fmaxf(acc[5] * inv, 0.f)) << 16);
    o.w = (unsigned)f2bf(fmaxf(acc[6] * inv, 0.f)) | ((unsigned)f2bf(fmaxf(acc[7] * inv, 0.f)) << 16);
    *(uint4*)(zout + (size_t)node * 128 + sl * 8) = o;
  }
}

// ---------------- semantic attention, MFMA-fused ----------------
__global__ __launch_bounds__(256) void satt_mfma_k(
    const us* __restrict__ z0, const us* __restrict__ z1,
    const us* __restrict__ Wat, const float* __restrict__ ba,
    const float* __restrict__ Wo, float* __restrict__ w_acc, int M)
{
  __shared__ us As[128 * 40];
  __shared__ us Bs[128 * 40];
  const us* Z = blockIdx.z ? z1 : z0;
  const int t = threadIdx.x;
  const int rowBase = blockIdx.y * 128;
  const int srow = t >> 1, sk = (t & 1) * 16;
  const int w = t >> 6, lane = t & 63;
  const int wm = w >> 1, wn = w & 1;
  const int m16 = lane & 15, q = lane >> 4;

  f32x4 acc[4][4];
  const f32x4 zero = {0.f, 0.f, 0.f, 0.f};
#pragma unroll
  for (int i = 0; i < 4; i++)
#pragma unroll
    for (int j = 0; j < 4; j++) acc[i][j] = zero;

  int arow = rowBase + srow;
  if (arow >= M) arow = M - 1;
  const us* aptr = Z + (size_t)arow * 128;
  const us* bptr = Wat + (size_t)srow * 128;

  for (int k0 = 0; k0 < 128; k0 += 32) {
    uint4 a0 = ((const uint4*)(aptr + k0 + sk))[0];
    uint4 a1 = ((const uint4*)(aptr + k0 + sk))[1];
    uint4 b0 = ((const uint4*)(bptr + k0 + sk))[0];
    uint4 b1 = ((const uint4*)(bptr + k0 + sk))[1];
    ((uint4*)&As[srow * 40 + sk])[0] = a0;
    ((uint4*)&As[srow * 40 + sk])[1] = a1;
    ((uint4*)&Bs[srow * 40 + sk])[0] = b0;
    ((uint4*)&Bs[srow * 40 + sk])[1] = b1;
    __syncthreads();
    s16x8 af[4], bfr[4];
#pragma unroll
    for (int mi = 0; mi < 4; mi++)
      af[mi] = *(const s16x8*)&As[(wm * 64 + mi * 16 + m16) * 40 + q * 8];
#pragma unroll
    for (int ni = 0; ni < 4; ni++)
      bfr[ni] = *(const s16x8*)&Bs[(wn * 64 + ni * 16 + m16) * 40 + q * 8];
#pragma unroll
    for (int mi = 0; mi < 4; mi++)
#pragma unroll
      for (int ni = 0; ni < 4; ni++)
        acc[mi][ni] = __builtin_amdgcn_mfma_f32_16x16x32_bf16(af[mi], bfr[ni], acc[mi][ni], 0, 0, 0);
    __syncthreads();
  }

  float s = 0.f;
#pragma unroll
  for (int ni = 0; ni < 4; ni++) {
    int col = wn * 64 + ni * 16 + m16;
    float bcol = ba[col], wcol = Wo[col];
#pragma unroll
    for (int mi = 0; mi < 4; mi++) {
#pragma unroll
      for (int r = 0; r < 4; r++) {
        int row = rowBase + wm * 64 + mi * 16 + q * 4 + r;
        if (row < M) s += tanhf(acc[mi][ni][r] + bcol) * wcol;
      }
    }
  }
  for (int d = 1; d < 64; d <<= 1) s += __shfl_xor(s, d);
  __shared__ float red[4];
  if (lane == 0) red[w] = s;
  __syncthreads();
  if (t == 0) atomicAdd(&w_acc[blockIdx.z], red[0] + red[1] + red[2] + red[3]);
}

__global__ void beta_k(const float* __restrict__ w_acc, float* __restrict__ beta, float invn) {
  if (threadIdx.x == 0 && blockIdx.x == 0) {
    float w0 = w_acc[0] * invn, w1 = w_acc[1] * invn;
    float m = fmaxf(w0, w1);
    float e0 = expf(w0 - m), e1 = expf(w1 - m);
    float s = e0 + e1;
    beta[0] = e0 / s; beta[1] = e1 / s;
    float w2 = w_acc[2] * invn, w3 = w_acc[3] * invn;
    float m2 = fmaxf(w2, w3);
    float e2 = expf(w2 - m2), e3 = expf(w3 - m2);
    float s2 = e2 + e3;
    beta[2] = e2 / s2; beta[3] = e3 / s2;
  }
}

static __device__ __forceinline__ unsigned int comb2(unsigned int a, unsigned int b, float b0, float b1) {
  float lo = bflo(a) * b0 + bflo(b) * b1;
  float hi = bfhi(a) * b0 + bfhi(b) * b1;
  return (unsigned int)f2bf(lo) | ((unsigned int)f2bf(hi) << 16);
}

__global__ __launch_bounds__(256) void combine2_k(const us* __restrict__ zb_all,
                                                  const float* __restrict__ beta,
                                                  us* __restrict__ haob, us* __restrict__ htob, int n8) {
  int z = blockIdx.z;
  const us* za = zb_all + (size_t)(2 * z) * N_NODES * 128;
  const us* zbv = zb_all + (size_t)(2 * z + 1) * N_NODES * 128;
  float b0 = beta[2 * z], b1 = beta[2 * z + 1];
  us* outv = z ? htob : haob;
  for (int i = blockIdx.x * 256 + threadIdx.x; i < n8; i += gridDim.x * 256) {
    uint4 a = ((const uint4*)za)[i];
    uint4 b = ((const uint4*)zbv)[i];
    uint4 o;
    o.x = comb2(a.x, b.x, b0, b1);
    o.y = comb2(a.y, b.y, b0, b1);
    o.z = comb2(a.z, b.z, b0, b1);
    o.w = comb2(a.w, b.w, b0, b1);
    ((uint4*)outv)[i] = o;
  }
}

// -------- predictor fully fused --------
__global__ __launch_bounds__(256) void pred_fused_k(
    const us* __restrict__ haob, const us* __restrict__ htob,
    const int* __restrict__ pos_e, const int* __restrict__ neg_e,
    const us* __restrict__ prW1t, const float* __restrict__ prb1,
    const float* __restrict__ prW2, const float* __restrict__ prb2,
    float* __restrict__ out, int M)
{
  __shared__ us As[128 * 40];
  __shared__ us Bs[128 * 40];
  const int z = blockIdx.z;
  const int* pe = z ? neg_e : pos_e;
  float* o = out + (size_t)z * M;

  const int t = threadIdx.x;
  const int rowBase = blockIdx.x * 128;
  const int srow = t >> 1, sk = (t & 1) * 16;
  const int w = t >> 6, lane = t & 63;
  const int wm = w >> 1, wn = w & 1;
  const int m16 = lane & 15, q = lane >> 4;

  f32x4 acc[4][4];
  const f32x4 zero = {0.f, 0.f, 0.f, 0.f};
#pragma unroll
  for (int i = 0; i < 4; i++)
#pragma unroll
    for (int j = 0; j < 4; j++) acc[i][j] = zero;

  int arow = rowBase + srow;
  if (arow >= M) arow = M - 1;
  const int srcn = pe[arow];
  const int dstn = pe[M + arow];
  const us* bptr = prW1t + (size_t)srow * 256;

  for (int k0 = 0; k0 < 256; k0 += 32) {
    const us* asrc = (k0 < 128) ? (haob + (size_t)srcn * 128 + k0 + sk)
                                : (htob + (size_t)dstn * 128 + (k0 - 128) + sk);
    uint4 a0 = ((const uint4*)asrc)[0];
    uint4 a1 = ((const uint4*)asrc)[1];
    uint4 b0 = ((const uint4*)(bptr + k0 + sk))[0];
    uint4 b1 = ((const uint4*)(bptr + k0 + sk))[1];
    ((uint4*)&As[srow * 40 + sk])[0] = a0;
    ((uint4*)&As[srow * 40 + sk])[1] = a1;
    ((uint4*)&Bs[srow * 40 + sk])[0] = b0;
    ((uint4*)&Bs[srow * 40 + sk])[1] = b1;
    __syncthreads();
    s16x8 af[4], bfr[4];
#pragma unroll
    for (int mi = 0; mi < 4; mi++)
      af[mi] = *(const s16x8*)&As[(wm * 64 + mi * 16 + m16) * 40 + q * 8];
#pragma unroll
    for (int ni = 0; ni < 4; ni++)
      bfr[ni] = *(const s16x8*)&Bs[(wn * 64 + ni * 16 + m16) * 40 + q * 8];
#pragma unroll
    for (int mi = 0; mi < 4; mi++)
#pragma unroll
      for (int ni = 0; ni < 4; ni++)
        acc[mi][ni] = __builtin_amdgcn_mfma_f32_16x16x32_bf16(af[mi], bfr[ni], acc[mi][ni], 0, 0, 0);
    __syncthreads();
  }

  float* rsum = (float*)As;
  if (t < 128) rsum[t] = 0.f;
  __syncthreads();
  float bcol[4], w2c[4];
#pragma unroll
  for (int ni = 0; ni < 4; ni++) {
    int col = wn * 64 + ni * 16 + m16;
    bcol[ni] = prb1[col];
    w2c[ni] = prW2[col];
  }
#pragma unroll
  for (int mi = 0; mi < 4; mi++) {
#pragma unroll
    for (int r = 0; r < 4; r++) {
      float s = 0.f;
#pragma unroll
      for (int ni = 0; ni < 4; ni++)
        s += fmaxf(acc[mi][ni][r] + bcol[ni], 0.f) * w2c[ni];
      s += __shfl_xor(s, 1);
      s += __shfl_xor(s, 2);
      s += __shfl_xor(s, 4);
      s += __shfl_xor(s, 8);
      if (m16 == 0) atomicAdd(&rsum[wm * 64 + mi * 16 + q * 4 + r], s);
    }
  }
  __syncthreads();
  if (t < 128) {
    int row = rowBase + t;
    if (row < M) o[row] = 1.f / (1.f + expf(-(rsum[t] + prb2[0])));
  }
}

extern "C" void kernel_launch(void* const* d_in, const int* in_sizes, int n_in,
                              void* d_out, int out_size, void* d_ws, size_t ws_size,
                              hipStream_t stream) {
  const float* PE   = (const float*)d_in[0];
  const float* GE   = (const float*)d_in[1];
  const float* W1   = (const float*)d_in[2];
  const float* b1   = (const float*)d_in[3];
  const float* W2   = (const float*)d_in[4];
  const float* b2   = (const float*)d_in[5];
  const float* gWs  = (const float*)d_in[6];
  const float* gbs  = (const float*)d_in[7];
  const float* gWd  = (const float*)d_in[8];
  const float* gbd  = (const float*)d_in[9];
  const float* gattn= (const float*)d_in[10];
  const float* pW1  = (const float*)d_in[11];
  const float* pb1  = (const float*)d_in[12];
  const float* pW2  = (const float*)d_in[13];
  const float* gaW1 = (const float*)d_in[14];
  const float* gab1 = (const float*)d_in[15];
  const float* gaW2 = (const float*)d_in[16];
  const float* prW1 = (const float*)d_in[17];
  const float* prb1 = (const float*)d_in[18];
  const float* prW2 = (const float*)d_in[19];
  const float* prb2 = (const float*)d_in[20];
  const int* e_aa = (const int*)d_in[21];
  const int* e_ta = (const int*)d_in[22];
  const int* e_tt = (const int*)d_in[23];
  const int* e_at = (const int*)d_in[24];
  const int* pos_e = (const int*)d_in[25];
  const int* neg_e = (const int*)d_in[26];
  float* out = (float*)d_out;

  // ---- workspace layout ----
  us* usws = (us*)d_ws;
  size_t o = 0;
  us* ha_b   = usws + o; o += (size_t)N_NODES * 256;
  us* ht_b   = usws + o; o += (size_t)N_NODES * 256;
  us* fs_all = usws + o; o += (size_t)8 * N_NODES * 128;
  us* zb_all = usws + o; o += (size_t)4 * N_NODES * 128;
  us* haob   = usws + o; o += (size_t)N_NODES * 128;
  us* htob   = usws + o; o += (size_t)N_NODES * 128;
  us* W2t    = usws + o; o += 262144;
  us* W1t    = usws + o; o += 131072;
  us* gWst   = usws + o; o += 131072;
  us* gWdt   = usws + o; o += 131072;
  us* prW1t  = usws + o; o += 32768;
  us* WaPt   = usws + o; o += 16384;
  us* WaGt   = usws + o; o += 16384;
  float* w_acc = (float*)(usws + o); o += 16;
  float* beta  = w_acc + 4;
  int* ib = (int*)(usws + o);
  size_t io = 0;
  int* bhist = ib + io; io += 1024;
  int* bbase = ib + io; io += 1024;
  int* bcur  = ib + io; io += 1024;
  int* offs4 = ib + io; io += NG4 + 4;
  int* esrc  = ib + io; io += ETOT;
  unsigned int* epack = (unsigned int*)zb_all;

  dim3 blk256(256), blk1024(1024);
  const int MT = idiv(N_NODES, 128);   // 391
  const int MT64 = idiv(N_NODES, 64);  // 782
  const int ET = idiv(EP_EDGES, 128);  // 1563

  // 1) weights
  wtrans_all_k<<<dim3(64, 1, 7), blk256, 0, stream>>>(
      W2, W1, gWs, gWd, prW1, pW1, gaW1, W2t, W1t, gWst, gWdt, prW1t, WaPt, WaGt);

  // 2) both input projections in one dispatch (64-row tiles for occupancy)
  proj2_gemm_k<<<dim3(MT64, 1, 2), blk256, 0, stream>>>(
      PE, GE, W2t, W1t, b2, b1, ha_b, ht_b, N_NODES);

  // 3) all 8 GAT feature GEMMs
  gat_gemm8_k<<<dim3(1, MT, 8), blk256, 0, stream>>>(ha_b, ht_b, gWst, gWdt, gbs, gbd, fs_all, N_NODES);

  // 4-7) CSR build v2 (bucketed two-phase, dense writes)
  hipMemsetAsync(bhist, 0, 4 * NBUCK * sizeof(int), stream);
  bhist_k<<<dim3(idiv(E_EDGES, 2048), 1, 4), blk256, 0, stream>>>(e_aa, e_ta, e_tt, e_at, bhist);
  bscan_k<<<1, blk1024, 0, stream>>>(bhist, bbase, bcur);
  binscatter_k<<<dim3(idiv(E_EDGES, 4096), 1, 4), blk256, 0, stream>>>(e_aa, e_ta, e_tt, e_at, bcur, epack);
  bucketscatter2_k<<<dim3(NBUCK, 1, 4), blk256, 0, stream>>>(bbase, epack, esrc, offs4);

  // 8) all 4 edge-softmax aggregations
  aggregate4_k<<<dim3(idiv(N_NODES, 4), 1, 4), blk256, 0, stream>>>(fs_all, gattn, offs4, esrc, zb_all, N_NODES);

  // 9-10) semantic attention
  hipMemsetAsync(w_acc, 0, 4 * sizeof(float), stream);
  satt_mfma_k<<<dim3(1, MT, 2), blk256, 0, stream>>>(
      zb_all, zb_all + (size_t)N_NODES * 128, WaPt, pb1, pW2, w_acc + 0, N_NODES);
  satt_mfma_k<<<dim3(1, MT, 2), blk256, 0, stream>>>(
      zb_all + (size_t)2 * N_NODES * 128, zb_all + (size_t)3 * N_NODES * 128, WaGt, gab1, gaW2, w_acc + 2, N_NODES);
  beta_k<<<1, 64, 0, stream>>>(w_acc, beta, 1.0f / (float)N_NODES);

  // 11) combine both groups
  combine2_k<<<dim3(2048, 1, 2), blk256, 0, stream>>>(zb_all, beta, haob, htob, N_NODES * 128 / 8);

  // 12) fully fused predictor (pos+neg)
  pred_fused_k<<<dim3(ET, 1, 2), blk256, 0, stream>>>(
      haob, htob, pos_e, neg_e, prW1t, prb1, prW2, prb2, out, EP_EDGES);
}